// Round 10
// baseline (4662.130 us; speedup 1.0000x reference)
//
#include <hip/hip_runtime.h>

typedef __attribute__((ext_vector_type(8))) short short8;
typedef __attribute__((ext_vector_type(4))) float f32x4;

__device__ __forceinline__ unsigned short f2bf(float f){
  unsigned u = __float_as_uint(f);
  u += 0x7FFFu + ((u >> 16) & 1u);
  return (unsigned short)(u >> 16);
}
__device__ __forceinline__ float sigm(float x){ return 1.f / (1.f + expf(-x)); }
__device__ __forceinline__ int aldr(const int* p){
  return __hip_atomic_load(p, __ATOMIC_RELAXED, __HIP_MEMORY_SCOPE_AGENT);
}

// ---------- prep kernels ----------

__global__ void k_embed_cvt(const float* __restrict__ e, unsigned short* __restrict__ ebf){
  long i = ((long)blockIdx.x * 256 + threadIdx.x) * 4;
  float4 v = *(const float4*)(e + i);
  ushort4 o;
  o.x = f2bf(v.x); o.y = f2bf(v.y); o.z = f2bf(v.z); o.w = f2bf(v.w);
  *(ushort4*)(ebf + i) = o;
}

// zero h1ring slot0, h2ring slot0, h2bf t=0 rows, all done flags; b2c = b_ih2+b_hh2
__global__ void k_prep_misc(const float* __restrict__ b_ih2, const float* __restrict__ b_hh2,
                            float* __restrict__ b2c, float* __restrict__ h1ring0,
                            float* __restrict__ h2ring0, unsigned short* __restrict__ h2bf0,
                            int* __restrict__ done){
  int i = blockIdx.x * 256 + threadIdx.x;   // 8192 threads
  h1ring0[i] = 0.f;
  h2ring0[i] = 0.f;
  h2bf0[i] = 0;
  if(i < 2048){ b2c[i] = b_ih2[i] + b_hh2[i]; }
  if(i < 4096){ done[i] = 0; }
}

// a1c[b][j] = b_ih1[j] + b_hh1[j] + sum_{k<512} embed[words[b][0]][k] * w_ih1[j][k]
__global__ void k_a1const(const int* __restrict__ words, const float* __restrict__ embed,
                          const float* __restrict__ w_ih1, const float* __restrict__ b_ih1,
                          const float* __restrict__ b_hh1, float* __restrict__ a1c){
  int bb = threadIdx.x & 15, jj = threadIdx.x >> 4;
  int j = blockIdx.x * 16 + jj;
  const float* x0 = embed + (long)words[bb * 256] * 512;
  const float* wr = w_ih1 + (long)j * 1024;
  float acc = 0.f;
  for(int k = 0; k < 512; k += 4){
    float4 a = *(const float4*)(x0 + k);
    float4 b = *(const float4*)(wr + k);
    acc += a.x*b.x + a.y*b.y + a.z*b.z + a.w*b.w;
  }
  a1c[bb * 2048 + j] = acc + b_ih1[j] + b_hh1[j];
}

// ---------- recurrent kernel: LDS-resident weights, merged L1+L2 per block ----------
// 256 blocks; block bl owns L1 hidden units {2bl,2bl+1} and L2 hidden units {2bl,2bl+1}.
// Lockstep: step s computes h1(s) (s<=255) and h2(s-1) (s>=2). One flag-barrier per step
// (relaxed poll + acquire fence / release store). Weights in LDS: zero per-step refetch.
// Does NOT use grid.sync -> only needs de-facto co-residency (256 blocks, 1/CU, idle GPU).
__global__ void __launch_bounds__(256) k_recur(
    const float* __restrict__ w_hh1, const float* __restrict__ w_ih2, const float* __restrict__ w_hh2,
    const float* __restrict__ a1c, const float* __restrict__ b2c,
    float* __restrict__ h1ring, float* __restrict__ h2ring, unsigned short* __restrict__ h2bf,
    int* done){
  __shared__ float W1[4096];    // [8 cols][512 k]  swizzled, 16KB
  __shared__ float W2[8192];    // [8 cols][1024 k] swizzled, 32KB
  __shared__ float red[512];    // cross-wave partials
  __shared__ float fin[256];    // final gate preactivations [2 layers][8 cols][16 b]
  const int bl = blockIdx.x, tid = threadIdx.x;
  const int cg = tid & 7, kg = (tid >> 3) & 15, bh = tid >> 7;

  // ---- stage weights into LDS (once) ----
  #pragma unroll
  for(int q = 0; q < 4; ++q){
    int idx = tid * 4 + q;                    // 0..1023 float4 slots
    int lc = idx >> 7, ks = idx & 127;        // col 0..7, k-slot 0..127
    int row = (lc >> 1) * 512 + bl * 2 + (lc & 1);
    float4 v = *(const float4*)(w_hh1 + (long)row * 512 + ks * 4);
    int ph = lc * 128 + (ks & ~7) + ((ks & 7) ^ ((lc + (ks >> 3)) & 7));
    *(float4*)(W1 + ph * 4) = v;
  }
  #pragma unroll
  for(int q = 0; q < 8; ++q){
    int idx = tid * 8 + q;                    // 0..2047 float4 slots
    int lc = idx >> 8, ks = idx & 255;        // col 0..7, k-slot 0..255
    int row = (lc >> 1) * 512 + bl * 2 + (lc & 1);
    int k4 = ks * 4;
    float4 v = (k4 < 512) ? *(const float4*)(w_ih2 + (long)row * 512 + k4)
                          : *(const float4*)(w_hh2 + (long)row * 512 + k4 - 512);
    int ph = lc * 256 + (ks & ~7) + ((ks & 7) ^ ((lc + (ks >> 3)) & 7));
    *(float4*)(W2 + ph * 4) = v;
  }
  // ---- per-finalize-thread bias + cell state ----
  float ag[4] = {0.f, 0.f, 0.f, 0.f};
  float cst = 0.f;
  if(tid < 32){
    int u = tid & 1, b = tid >> 1;
    #pragma unroll
    for(int g = 0; g < 4; ++g) ag[g] = a1c[b * 2048 + g * 512 + bl * 2 + u];
  } else if(tid < 64){
    int u = (tid - 32) & 1;
    #pragma unroll
    for(int g = 0; g < 4; ++g) ag[g] = b2c[g * 512 + bl * 2 + u];
  }
  __syncthreads();

  for(int s = 1; s <= 256; ++s){
    // ---- wait: all 256 blocks finished step s-1 ----
    if(tid < 64){
      if(s > 1){
        for(;;){
          int ok = 1;
          #pragma unroll
          for(int q = 0; q < 4; ++q) ok &= (aldr(done + (tid * 4 + q) * 16) >= s - 1);
          if(__all(ok)) break;
          __builtin_amdgcn_s_sleep(1);
        }
      }
      __builtin_amdgcn_fence(__ATOMIC_ACQUIRE, "agent");   // invalidate L2: fresh h
    }
    __syncthreads();

    float accL1[8] = {0.f,0.f,0.f,0.f,0.f,0.f,0.f,0.f};
    float accL2[8] = {0.f,0.f,0.f,0.f,0.f,0.f,0.f,0.f};

    if(s <= 255){  // L1: h1(s) partial dot: col cg, k = kg*32..+32, b = bh*8..+8
      const float* hp = h1ring + ((s - 1) & 1) * 8192 + (bh * 8) * 512 + kg * 32;
      #pragma unroll
      for(int j = 0; j < 8; ++j){
        int slot = cg * 128 + kg * 8 + (j ^ ((cg + kg) & 7));
        float4 wv = *(const float4*)(W1 + slot * 4);
        #pragma unroll
        for(int b8 = 0; b8 < 8; ++b8){
          float4 hv = *(const float4*)(hp + b8 * 512 + j * 4);
          accL1[b8] += hv.x*wv.x + hv.y*wv.y + hv.z*wv.z + hv.w*wv.w;
        }
      }
    }
    if(s >= 2){    // L2: h2(s-1) partial dot: col cg, K=1024 (h1(s-1) | h2(s-2))
      const float* h1p = h1ring + ((s - 1) & 1) * 8192 + (bh * 8) * 512;
      const float* h2p = h2ring + (s & 1) * 8192 + (bh * 8) * 512;   // (s-2)&1 == s&1
      #pragma unroll
      for(int j = 0; j < 16; ++j){
        int ks = kg * 16 + j;                 // 0..255
        int slot = cg * 256 + (ks & ~7) + ((ks & 7) ^ ((cg + (ks >> 3)) & 7));
        float4 wv = *(const float4*)(W2 + slot * 4);
        int k4 = ks * 4;                      // 0..1023
        const float* hsrc = (k4 < 512) ? (h1p + k4) : (h2p + k4 - 512);
        #pragma unroll
        for(int b8 = 0; b8 < 8; ++b8){
          float4 hv = *(const float4*)(hsrc + b8 * 512);
          accL2[b8] += hv.x*wv.x + hv.y*wv.y + hv.z*wv.z + hv.w*wv.w;
        }
      }
    }

    // ---- reduce over kg: in-wave shuffle (lane bits 3..5), then cross-wave via LDS ----
    #pragma unroll
    for(int m = 8; m <= 32; m <<= 1){
      #pragma unroll
      for(int b8 = 0; b8 < 8; ++b8){
        accL1[b8] += __shfl_xor(accL1[b8], m);
        accL2[b8] += __shfl_xor(accL2[b8], m);
      }
    }
    if((tid & 56) == 0){                      // one lane per (wave, cg)
      int w = tid >> 6; int bh_ = w >> 1, kgh = w & 1;
      #pragma unroll
      for(int b8 = 0; b8 < 8; ++b8){
        red[((bh_ * 2 + kgh) * 2 + 0) * 64 + cg * 8 + b8] = accL1[b8];
        red[((bh_ * 2 + kgh) * 2 + 1) * 64 + cg * 8 + b8] = accL2[b8];
      }
    }
    __syncthreads();
    {
      int l = tid >> 7, cgf = (tid >> 4) & 7, bf = tid & 15;
      int bh_ = bf >> 3, b8 = bf & 7;
      fin[l * 128 + cgf * 16 + bf] =
          red[((bh_ * 2 + 0) * 2 + l) * 64 + cgf * 8 + b8]
        + red[((bh_ * 2 + 1) * 2 + l) * 64 + cgf * 8 + b8];
    }
    __syncthreads();

    // ---- gate nonlinearity + h writes ----
    if(tid < 32){
      if(s <= 255){
        int u = tid & 1, b = tid >> 1;
        float g0 = fin[(0 * 2 + u) * 16 + b] + ag[0];
        float g1 = fin[(1 * 2 + u) * 16 + b] + ag[1];
        float g2 = fin[(2 * 2 + u) * 16 + b] + ag[2];
        float g3 = fin[(3 * 2 + u) * 16 + b] + ag[3];
        cst = sigm(g1) * cst + sigm(g0) * tanhf(g2);
        float h = sigm(g3) * tanhf(cst);
        h1ring[(s & 1) * 8192 + b * 512 + bl * 2 + u] = h;
      }
    } else if(tid < 64){
      if(s >= 2){
        int u = (tid - 32) & 1, b = (tid - 32) >> 1;
        float g0 = fin[128 + (0 * 2 + u) * 16 + b] + ag[0];
        float g1 = fin[128 + (1 * 2 + u) * 16 + b] + ag[1];
        float g2 = fin[128 + (2 * 2 + u) * 16 + b] + ag[2];
        float g3 = fin[128 + (3 * 2 + u) * 16 + b] + ag[3];
        cst = sigm(g1) * cst + sigm(g0) * tanhf(g2);
        float h = sigm(g3) * tanhf(cst);
        h2ring[((s - 1) & 1) * 8192 + b * 512 + bl * 2 + u] = h;
        h2bf[((long)(s - 1) * 16 + b) * 512 + bl * 2 + u] = f2bf(h);
      }
    }
    __syncthreads();                          // drains vmcnt: h stores committed
    if(s <= 255 && tid == 0)
      __hip_atomic_store(done + bl * 16, s, __ATOMIC_RELEASE, __HIP_MEMORY_SCOPE_AGENT);
  }
}

// ---------- projection GEMM (unchanged, passing) ----------
__global__ void __launch_bounds__(256, 2) k_proj(const unsigned short* __restrict__ A,
                                                 const unsigned short* __restrict__ Bm,
                                                 const float* __restrict__ fc_b,
                                                 float* __restrict__ out){
  __shared__ __align__(16) unsigned short As[4096];   // [128][32]
  __shared__ __align__(16) unsigned short Bs[4096];   // [128][32]
  const int tid = threadIdx.x;
  const int lane = tid & 63, w = tid >> 6;
  const int wr = w >> 1, wc = w & 1;
  const long mbase = (long)blockIdx.y * 128;
  const long nbase = (long)blockIdx.x * 128;
  f32x4 acc[4][4] = {};

  const int lrow = lane >> 2;
  const int lcol = (lane & 3) * 8;
  for(int kt = 0; kt < 16; ++kt){
    #pragma unroll
    for(int r = 0; r < 2; ++r){
      const unsigned short* ga = A  + (mbase + r*64 + w*16 + lrow) * 512 + kt*32 + lcol;
      __builtin_amdgcn_global_load_lds((const __attribute__((address_space(1))) void*)ga,
          (__attribute__((address_space(3))) void*)((char*)As + r*4096 + w*1024), 16, 0, 0);
      const unsigned short* gb = Bm + (nbase + r*64 + w*16 + lrow) * 512 + kt*32 + lcol;
      __builtin_amdgcn_global_load_lds((const __attribute__((address_space(1))) void*)gb,
          (__attribute__((address_space(3))) void*)((char*)Bs + r*4096 + w*1024), 16, 0, 0);
    }
    __syncthreads();
    short8 af[4], bf[4];
    const int kro = (lane >> 4) * 8;
    #pragma unroll
    for(int m = 0; m < 4; ++m){
      af[m] = *(const short8*)(As + (wr*64 + m*16 + (lane & 15)) * 32 + kro);
      bf[m] = *(const short8*)(Bs + (wc*64 + m*16 + (lane & 15)) * 32 + kro);
    }
    #pragma unroll
    for(int m = 0; m < 4; ++m){
      #pragma unroll
      for(int n = 0; n < 4; ++n){
        acc[m][n] = __builtin_amdgcn_mfma_f32_16x16x32_bf16(af[m], bf[n], acc[m][n], 0, 0, 0);
      }
    }
    __syncthreads();
  }
  const int crow0 = (lane >> 4) * 4;
  const int ccol = lane & 15;
  float fb[4];
  #pragma unroll
  for(int n = 0; n < 4; ++n) fb[n] = fc_b[nbase + wc*64 + n*16 + ccol];
  #pragma unroll
  for(int m = 0; m < 4; ++m){
    #pragma unroll
    for(int j = 0; j < 4; ++j){
      long rr = mbase + wr*64 + m*16 + crow0 + j;
      int t = (int)(rr >> 4), b = (int)(rr & 15);
      float* orow = out + ((long)b * 256 + t) * 32000;
      #pragma unroll
      for(int n = 0; n < 4; ++n){
        float v = (t == 0) ? 0.f : (acc[m][n][j] + fb[n]);
        orow[nbase + wc*64 + n*16 + ccol] = v;
      }
    }
  }
}

extern "C" void kernel_launch(void* const* d_in, const int* in_sizes, int n_in,
                              void* d_out, int out_size, void* d_ws, size_t ws_size,
                              hipStream_t stream){
  const int*   words = (const int*)  d_in[0];
  const float* embed = (const float*)d_in[1];
  const float* fc_b  = (const float*)d_in[2];
  const float* w_ih1 = (const float*)d_in[3];
  const float* w_hh1 = (const float*)d_in[4];
  const float* b_ih1 = (const float*)d_in[5];
  const float* b_hh1 = (const float*)d_in[6];
  const float* w_ih2 = (const float*)d_in[7];
  const float* w_hh2 = (const float*)d_in[8];
  const float* b_ih2 = (const float*)d_in[9];
  const float* b_hh2 = (const float*)d_in[10];
  float* out = (float*)d_out;
  char* ws = (char*)d_ws;

  unsigned short* embed_bf = (unsigned short*)(ws + 0);          // 32,768,000 B
  unsigned short* h2bf     = (unsigned short*)(ws + 32768000);   //  4,194,304 B (4096x512)
  float* h1ring = (float*)(ws + 36962304);                       //     65,536 B (2 x 16x512)
  float* h2ring = (float*)(ws + 37027840);                       //     65,536 B
  float* a1c    = (float*)(ws + 37093376);                       //    131,072 B (16x2048)
  float* b2c    = (float*)(ws + 37224448);                       //      8,192 B
  int*   done   = (int*)  (ws + 37232640);                       //     16,384 B (256 x 16 ints)
  // total 37,249,024 B

  k_embed_cvt<<<16000, 256, 0, stream>>>(embed, embed_bf);
  k_prep_misc<<<32, 256, 0, stream>>>(b_ih2, b_hh2, b2c, h1ring, h2ring, h2bf, done);
  k_a1const<<<128, 256, 0, stream>>>(words, embed, w_ih1, b_ih1, b_hh1, a1c);

  // k_recur never calls grid.sync(); it only needs de-facto co-residency.
  // Try cooperative launch (gives the guarantee); if the runtime rejects it
  // (the silent failure mode of R3/R5/R6/R8/R9), fall back to a plain launch.
  void* args[9];
  args[0] = (void*)&w_hh1; args[1] = (void*)&w_ih2; args[2] = (void*)&w_hh2;
  args[3] = (void*)&a1c;   args[4] = (void*)&b2c;
  args[5] = (void*)&h1ring; args[6] = (void*)&h2ring; args[7] = (void*)&h2bf;
  args[8] = (void*)&done;
  hipError_t ce = hipLaunchCooperativeKernel((const void*)k_recur, dim3(256), dim3(256),
                                             args, 0, stream);
  if(ce != hipSuccess){
    k_recur<<<dim3(256), dim3(256), 0, stream>>>(w_hh1, w_ih2, w_hh2, a1c, b2c,
                                                 h1ring, h2ring, h2bf, done);
  }

  k_proj<<<dim3(250, 32), 256, 0, stream>>>(h2bf, embed_bf, fc_b, out);
}

// Round 11
// 3186.148 us; speedup vs baseline: 1.4632x; 1.4632x over previous
//
#include <hip/hip_runtime.h>
#include <hip/hip_fp16.h>

typedef __attribute__((ext_vector_type(8))) short short8;
typedef __attribute__((ext_vector_type(8))) unsigned short ushort8;
typedef __attribute__((ext_vector_type(4))) float f32x4;

__device__ __forceinline__ unsigned short f2bf(float f){
  unsigned u = __float_as_uint(f);
  u += 0x7FFFu + ((u >> 16) & 1u);
  return (unsigned short)(u >> 16);
}
__device__ __forceinline__ float sigm(float x){ return 1.f / (1.f + expf(-x)); }
__device__ __forceinline__ int aldr(const int* p){
  return __hip_atomic_load(p, __ATOMIC_RELAXED, __HIP_MEMORY_SCOPE_AGENT);
}

// ---------- prep kernels ----------

__global__ void k_embed_cvt(const float* __restrict__ e, unsigned short* __restrict__ ebf){
  long i = ((long)blockIdx.x * 256 + threadIdx.x) * 4;
  float4 v = *(const float4*)(e + i);
  ushort4 o;
  o.x = f2bf(v.x); o.y = f2bf(v.y); o.z = f2bf(v.z); o.w = f2bf(v.w);
  *(ushort4*)(ebf + i) = o;
}

__global__ void k_prep_misc(const float* __restrict__ b_ih2, const float* __restrict__ b_hh2,
                            float* __restrict__ b2c, float* __restrict__ h1ring0,
                            float* __restrict__ h2ring0, unsigned short* __restrict__ h2bf0,
                            int* __restrict__ done){
  int i = blockIdx.x * 256 + threadIdx.x;   // 8192 threads
  h1ring0[i] = 0.f;
  h2ring0[i] = 0.f;
  h2bf0[i] = 0;
  if(i < 2048){ b2c[i] = b_ih2[i] + b_hh2[i]; }
  if(i < 4096){ done[i] = 0; }
}

__global__ void k_a1const(const int* __restrict__ words, const float* __restrict__ embed,
                          const float* __restrict__ w_ih1, const float* __restrict__ b_ih1,
                          const float* __restrict__ b_hh1, float* __restrict__ a1c){
  int bb = threadIdx.x & 15, jj = threadIdx.x >> 4;
  int j = blockIdx.x * 16 + jj;
  const float* x0 = embed + (long)words[bb * 256] * 512;
  const float* wr = w_ih1 + (long)j * 1024;
  float acc = 0.f;
  for(int k = 0; k < 512; k += 4){
    float4 a = *(const float4*)(x0 + k);
    float4 b = *(const float4*)(wr + k);
    acc += a.x*b.x + a.y*b.y + a.z*b.z + a.w*b.w;
  }
  a1c[bb * 2048 + j] = acc + b_ih1[j] + b_hh1[j];
}

// ---------- recurrent kernel: LDS weights + coalesced LDS h-staging ----------
// 256 blocks. bl<128: layer-1, 4 units (fp32 W, 32KB) + 32KB h1 stage.
// bl>=128: layer-2, 4 units (fp16 W, 32KB) + 32KB stage reused for h1(t) then h2(t-1).
// Flag sync per step: relaxed poll + acquire fence / release store (R4/R7/R10 proven).
// No grid.sync -> coop launch with plain fallback is safe.
__global__ void __launch_bounds__(256) k_recur(
    const float* __restrict__ w_hh1, const float* __restrict__ w_ih2, const float* __restrict__ w_hh2,
    const float* __restrict__ a1c, const float* __restrict__ b2c,
    float* __restrict__ h1ring, float* __restrict__ h2ring, unsigned short* __restrict__ h2bf,
    int* done){
  __shared__ float smem[16384];           // 64KB: [0..8192) = W, [8192..16384) = stage/partials
  float* stg = smem + 8192;
  int* done1 = done;                      // flag i at done1[i*16]
  int* done2 = done + 2048;
  const int bl = blockIdx.x, tid = threadIdx.x;
  const int cg = tid & 3, kg = (tid >> 2) & 31, bh = tid >> 7;
  const int xr = (kg >> 1) & 7;
  const bool isL1 = (bl < 128);
  const int ubase = (isL1 ? bl : bl - 128) * 4;
  const int gb = tid >> 4, gu = tid & 3;            // gate lane's (b, u)
  const bool gate = ((tid & 12) == 0);

  // ---- stage weights into LDS (once) ----
  if(isL1){
    #pragma unroll
    for(int q = 0; q < 8; ++q){
      int f = q * 256 + tid;                        // 0..2047 float4 slots
      int col = f >> 7, sk = f & 127;               // col = g*4+u
      int row = (col >> 2) * 512 + ubase + (col & 3);
      float4 v = *(const float4*)(w_hh1 + (long)row * 512 + sk * 4);
      int key = (col + (col >> 2)) & 7;
      *(float4*)(smem + col * 512 + (sk ^ key) * 4) = v;
    }
  } else {
    unsigned short* W2 = (unsigned short*)smem;     // 16 cols x 1024 fp16
    #pragma unroll
    for(int q = 0; q < 8; ++q){
      int f = q * 256 + tid;                        // 0..2047 ushort8 slots
      int col = f >> 7, sk = f & 127;
      int row = (col >> 2) * 512 + ubase + (col & 3);
      int k = sk * 8;
      const float* srcw = (k < 512) ? (w_ih2 + (long)row * 512 + k)
                                    : (w_hh2 + (long)row * 512 + (k - 512));
      float4 va = *(const float4*)(srcw);
      float4 vb = *(const float4*)(srcw + 4);
      ushort8 o;
      o[0] = __half_as_ushort(__float2half(va.x)); o[1] = __half_as_ushort(__float2half(va.y));
      o[2] = __half_as_ushort(__float2half(va.z)); o[3] = __half_as_ushort(__float2half(va.w));
      o[4] = __half_as_ushort(__float2half(vb.x)); o[5] = __half_as_ushort(__float2half(vb.y));
      o[6] = __half_as_ushort(__float2half(vb.z)); o[7] = __half_as_ushort(__float2half(vb.w));
      int key = (col + (col >> 2)) & 7;
      *(ushort8*)(W2 + col * 1024 + (sk ^ key) * 8) = o;
    }
  }
  // gate-lane bias + cell state
  float ag[4] = {0.f, 0.f, 0.f, 0.f};
  float cst = 0.f;
  if(gate){
    #pragma unroll
    for(int g = 0; g < 4; ++g)
      ag[g] = isL1 ? a1c[gb * 2048 + g * 512 + ubase + gu] : b2c[g * 512 + ubase + gu];
  }
  __syncthreads();

  for(int s = 1; s <= 255; ++s){
    // ---- poll + acquire ----
    if(tid < 64){
      for(;;){
        int ok;
        if(isL1){
          ok = (s == 1) ? 1 : ((aldr(done1 + tid * 16) >= s - 1) &
                               (aldr(done1 + (64 + tid) * 16) >= s - 1));
          if(s >= 65) ok &= (aldr(done2 + tid * 16) >= s - 64) &
                            (aldr(done2 + (64 + tid) * 16) >= s - 64);
        } else {
          ok = (aldr(done1 + tid * 16) >= s) & (aldr(done1 + (64 + tid) * 16) >= s);
          if(s > 1) ok &= (aldr(done2 + tid * 16) >= s - 1) &
                          (aldr(done2 + (64 + tid) * 16) >= s - 1);
        }
        if(__all(ok)) break;
        __builtin_amdgcn_s_sleep(1);
      }
      __builtin_amdgcn_fence(__ATOMIC_ACQUIRE, "agent");   // invalidate L2: fresh h
    }
    __syncthreads();

    float acc[8][4] = {};
    const int nph = isL1 ? 1 : 2;
    for(int p = 0; p < nph; ++p){
      // ---- stage h chunk: 32KB coalesced, XOR-swizzled ----
      const float* src = isL1 ? (h1ring + ((s - 1) & 63) * 8192)
                              : (p == 0 ? (h1ring + (s & 63) * 8192)
                                        : (h2ring + ((s - 1) & 1) * 8192));
      #pragma unroll
      for(int q = 0; q < 8; ++q){
        int f = q * 256 + tid;
        *(float4*)(stg + 4 * (f ^ ((f >> 3) & 7))) = *(const float4*)(src + 4 * f);
      }
      __syncthreads();
      // ---- dot: col cg*4..+3, k = kg*16..+16 (of this 512-chunk), b = bh*8..+8 ----
      if(isL1){
        #pragma unroll
        for(int jb = 0; jb < 4; ++jb){
          int sk = kg * 4 + jb;
          float4 wv[4];
          #pragma unroll
          for(int cc = 0; cc < 4; ++cc){
            int col = cg * 4 + cc;
            wv[cc] = *(const float4*)(smem + col * 512 + ((sk ^ ((col + (col >> 2)) & 7)) * 4));
          }
          #pragma unroll
          for(int b8 = 0; b8 < 8; ++b8){
            int slot = (bh * 8 + b8) * 128 + sk;
            float4 hv = *(const float4*)(stg + 4 * (slot ^ xr));
            #pragma unroll
            for(int cc = 0; cc < 4; ++cc)
              acc[b8][cc] += hv.x*wv[cc].x + hv.y*wv[cc].y + hv.z*wv[cc].z + hv.w*wv[cc].w;
          }
        }
      } else {
        const unsigned short* W2 = (const unsigned short*)smem;
        #pragma unroll
        for(int jbp = 0; jbp < 2; ++jbp){
          float wf[4][8];
          #pragma unroll
          for(int cc = 0; cc < 4; ++cc){
            int col = cg * 4 + cc;
            int sk = p * 64 + kg * 2 + jbp;
            ushort8 wv = *(const ushort8*)(W2 + col * 1024 + ((sk ^ ((col + (col >> 2)) & 7)) * 8));
            #pragma unroll
            for(int e = 0; e < 8; ++e) wf[cc][e] = __half2float(__ushort_as_half(wv[e]));
          }
          #pragma unroll
          for(int b8 = 0; b8 < 8; ++b8){
            int slot0 = (bh * 8 + b8) * 128 + kg * 4 + jbp * 2;
            float4 h0 = *(const float4*)(stg + 4 * (slot0 ^ xr));
            float4 h1v = *(const float4*)(stg + 4 * ((slot0 + 1) ^ xr));
            #pragma unroll
            for(int cc = 0; cc < 4; ++cc)
              acc[b8][cc] += h0.x*wf[cc][0] + h0.y*wf[cc][1] + h0.z*wf[cc][2] + h0.w*wf[cc][3]
                           + h1v.x*wf[cc][4] + h1v.y*wf[cc][5] + h1v.z*wf[cc][6] + h1v.w*wf[cc][7];
          }
        }
      }
      __syncthreads();   // stage reads done (next phase overwrites / partials reuse)
    }

    // ---- partials to LDS: part[b][kg][col16] ----
    #pragma unroll
    for(int b8 = 0; b8 < 8; ++b8){
      int b = bh * 8 + b8;
      *(float4*)(stg + ((b * 32 + kg) * 16 + cg * 4)) =
          make_float4(acc[b8][0], acc[b8][1], acc[b8][2], acc[b8][3]);
    }
    __syncthreads();
    // ---- reduce over kg: thread (b,col) = (tid>>4, tid&15) ----
    float sum = 0.f;
    {
      int b = tid >> 4, col = tid & 15;
      #pragma unroll
      for(int k2 = 0; k2 < 32; ++k2) sum += stg[(b * 32 + k2) * 16 + col];
    }
    // gather the 4 gates for (b,u) into gate lanes via in-wave shuffle
    {
      int r = tid & 63;
      float gv[4];
      #pragma unroll
      for(int g = 0; g < 4; ++g) gv[g] = __shfl(sum, (r & 48) + g * 4 + (r & 3), 64);
      if(gate){
        float g0 = gv[0] + ag[0], g1 = gv[1] + ag[1], g2 = gv[2] + ag[2], g3 = gv[3] + ag[3];
        cst = sigm(g1) * cst + sigm(g0) * tanhf(g2);
        float h = sigm(g3) * tanhf(cst);
        if(isL1){
          h1ring[(s & 63) * 8192 + gb * 512 + ubase + gu] = h;
        } else {
          h2ring[(s & 1) * 8192 + gb * 512 + ubase + gu] = h;
          h2bf[((long)s * 16 + gb) * 512 + ubase + gu] = f2bf(h);
        }
      }
    }
    __syncthreads();                      // drains vmcnt: h stores committed to local L2
    if(tid == 0){
      if(isL1) __hip_atomic_store(done1 + bl * 16, s, __ATOMIC_RELEASE, __HIP_MEMORY_SCOPE_AGENT);
      else     __hip_atomic_store(done2 + (bl - 128) * 16, s, __ATOMIC_RELEASE, __HIP_MEMORY_SCOPE_AGENT);
    }
  }
}

// ---------- projection GEMM (unchanged, passing) ----------
__global__ void __launch_bounds__(256, 2) k_proj(const unsigned short* __restrict__ A,
                                                 const unsigned short* __restrict__ Bm,
                                                 const float* __restrict__ fc_b,
                                                 float* __restrict__ out){
  __shared__ __align__(16) unsigned short As[4096];   // [128][32]
  __shared__ __align__(16) unsigned short Bs[4096];   // [128][32]
  const int tid = threadIdx.x;
  const int lane = tid & 63, w = tid >> 6;
  const int wr = w >> 1, wc = w & 1;
  const long mbase = (long)blockIdx.y * 128;
  const long nbase = (long)blockIdx.x * 128;
  f32x4 acc[4][4] = {};

  const int lrow = lane >> 2;
  const int lcol = (lane & 3) * 8;
  for(int kt = 0; kt < 16; ++kt){
    #pragma unroll
    for(int r = 0; r < 2; ++r){
      const unsigned short* ga = A  + (mbase + r*64 + w*16 + lrow) * 512 + kt*32 + lcol;
      __builtin_amdgcn_global_load_lds((const __attribute__((address_space(1))) void*)ga,
          (__attribute__((address_space(3))) void*)((char*)As + r*4096 + w*1024), 16, 0, 0);
      const unsigned short* gb = Bm + (nbase + r*64 + w*16 + lrow) * 512 + kt*32 + lcol;
      __builtin_amdgcn_global_load_lds((const __attribute__((address_space(1))) void*)gb,
          (__attribute__((address_space(3))) void*)((char*)Bs + r*4096 + w*1024), 16, 0, 0);
    }
    __syncthreads();
    short8 af[4], bf[4];
    const int kro = (lane >> 4) * 8;
    #pragma unroll
    for(int m = 0; m < 4; ++m){
      af[m] = *(const short8*)(As + (wr*64 + m*16 + (lane & 15)) * 32 + kro);
      bf[m] = *(const short8*)(Bs + (wc*64 + m*16 + (lane & 15)) * 32 + kro);
    }
    #pragma unroll
    for(int m = 0; m < 4; ++m){
      #pragma unroll
      for(int n = 0; n < 4; ++n){
        acc[m][n] = __builtin_amdgcn_mfma_f32_16x16x32_bf16(af[m], bf[n], acc[m][n], 0, 0, 0);
      }
    }
    __syncthreads();
  }
  const int crow0 = (lane >> 4) * 4;
  const int ccol = lane & 15;
  float fb[4];
  #pragma unroll
  for(int n = 0; n < 4; ++n) fb[n] = fc_b[nbase + wc*64 + n*16 + ccol];
  #pragma unroll
  for(int m = 0; m < 4; ++m){
    #pragma unroll
    for(int j = 0; j < 4; ++j){
      long rr = mbase + wr*64 + m*16 + crow0 + j;
      int t = (int)(rr >> 4), b = (int)(rr & 15);
      float* orow = out + ((long)b * 256 + t) * 32000;
      #pragma unroll
      for(int n = 0; n < 4; ++n){
        float v = (t == 0) ? 0.f : (acc[m][n][j] + fb[n]);
        orow[nbase + wc*64 + n*16 + ccol] = v;
      }
    }
  }
}

extern "C" void kernel_launch(void* const* d_in, const int* in_sizes, int n_in,
                              void* d_out, int out_size, void* d_ws, size_t ws_size,
                              hipStream_t stream){
  const int*   words = (const int*)  d_in[0];
  const float* embed = (const float*)d_in[1];
  const float* fc_b  = (const float*)d_in[2];
  const float* w_ih1 = (const float*)d_in[3];
  const float* w_hh1 = (const float*)d_in[4];
  const float* b_ih1 = (const float*)d_in[5];
  const float* b_hh1 = (const float*)d_in[6];
  const float* w_ih2 = (const float*)d_in[7];
  const float* w_hh2 = (const float*)d_in[8];
  const float* b_ih2 = (const float*)d_in[9];
  const float* b_hh2 = (const float*)d_in[10];
  float* out = (float*)d_out;
  char* ws = (char*)d_ws;

  unsigned short* embed_bf = (unsigned short*)(ws + 0);          // 32,768,000 B
  unsigned short* h2bf     = (unsigned short*)(ws + 32768000);   //  4,194,304 B (4096x512)
  float* h1ring = (float*)(ws + 36962304);                       //  2,097,152 B (64 x 16x512)
  float* h2ring = (float*)(ws + 39059456);                       //     65,536 B (2 x 16x512)
  float* a1c    = (float*)(ws + 39124992);                       //    131,072 B (16x2048)
  float* b2c    = (float*)(ws + 39256064);                       //      8,192 B
  int*   done   = (int*)  (ws + 39264256);                       //     16,384 B (4096 ints)
  // total 39,280,640 B

  k_embed_cvt<<<16000, 256, 0, stream>>>(embed, embed_bf);
  k_prep_misc<<<32, 256, 0, stream>>>(b_ih2, b_hh2, b2c, h1ring, h2ring, h2bf, done);
  k_a1const<<<128, 256, 0, stream>>>(words, embed, w_ih1, b_ih1, b_hh1, a1c);

  // k_recur needs only de-facto co-residency (no grid.sync). Coop launch when the
  // runtime accepts it; otherwise plain launch (the R3..R9 silent-failure fix).
  void* args[9];
  args[0] = (void*)&w_hh1; args[1] = (void*)&w_ih2; args[2] = (void*)&w_hh2;
  args[3] = (void*)&a1c;   args[4] = (void*)&b2c;
  args[5] = (void*)&h1ring; args[6] = (void*)&h2ring; args[7] = (void*)&h2bf;
  args[8] = (void*)&done;
  hipError_t ce = hipLaunchCooperativeKernel((const void*)k_recur, dim3(256), dim3(256),
                                             args, 0, stream);
  if(ce != hipSuccess){
    k_recur<<<dim3(256), dim3(256), 0, stream>>>(w_hh1, w_ih2, w_hh2, a1c, b2c,
                                                 h1ring, h2ring, h2bf, done);
  }

  k_proj<<<dim3(250, 32), 256, 0, stream>>>(h2bf, embed_bf, fc_b, out);
}

// Round 12
// 2183.228 us; speedup vs baseline: 2.1354x; 1.4594x over previous
//
#include <hip/hip_runtime.h>
#include <hip/hip_fp16.h>

typedef __attribute__((ext_vector_type(8))) short short8;
typedef __attribute__((ext_vector_type(8))) unsigned short ushort8;
typedef __attribute__((ext_vector_type(4))) float f32x4;
typedef unsigned long long ull;

__device__ __forceinline__ unsigned short f2bf(float f){
  unsigned u = __float_as_uint(f);
  u += 0x7FFFu + ((u >> 16) & 1u);
  return (unsigned short)(u >> 16);
}
__device__ __forceinline__ float sigm(float x){ return 1.f / (1.f + expf(-x)); }
__device__ __forceinline__ int aldr(const int* p){
  return __hip_atomic_load(p, __ATOMIC_RELAXED, __HIP_MEMORY_SCOPE_AGENT);
}
__device__ __forceinline__ ull ald8(const ull* p){
  return __hip_atomic_load(p, __ATOMIC_RELAXED, __HIP_MEMORY_SCOPE_AGENT);
}
__device__ __forceinline__ void ast8(ull* p, ull v){
  __hip_atomic_store(p, v, __ATOMIC_RELAXED, __HIP_MEMORY_SCOPE_AGENT);
}
__device__ __forceinline__ void asti(int* p, int v){
  __hip_atomic_store(p, v, __ATOMIC_RELAXED, __HIP_MEMORY_SCOPE_AGENT);
}
__device__ __forceinline__ ull packh(float h, unsigned tag){
  return ((ull)tag << 32) | (ull)__float_as_uint(h);
}

// ---------- prep kernels ----------

__global__ void k_embed_cvt(const float* __restrict__ e, unsigned short* __restrict__ ebf){
  long i = ((long)blockIdx.x * 256 + threadIdx.x) * 4;
  float4 v = *(const float4*)(e + i);
  ushort4 o;
  o.x = f2bf(v.x); o.y = f2bf(v.y); o.z = f2bf(v.z); o.w = f2bf(v.w);
  *(ushort4*)(ebf + i) = o;
}

// re-zero slot 0 of both tagged rings (tag0 = step-0 zeros), h2bf t=0 rows, prog flags
__global__ void k_prep_misc(const float* __restrict__ b_ih2, const float* __restrict__ b_hh2,
                            float* __restrict__ b2c, ull* __restrict__ h1tag0,
                            ull* __restrict__ h2tag0, unsigned short* __restrict__ h2bf0,
                            int* __restrict__ done){
  int i = blockIdx.x * 256 + threadIdx.x;   // 8192 threads
  h1tag0[i] = 0ull;
  h2tag0[i] = 0ull;
  h2bf0[i] = 0;
  if(i < 2048){ b2c[i] = b_ih2[i] + b_hh2[i]; }
  if(i < 4096){ done[i] = 0; }
}

__global__ void k_a1const(const int* __restrict__ words, const float* __restrict__ embed,
                          const float* __restrict__ w_ih1, const float* __restrict__ b_ih1,
                          const float* __restrict__ b_hh1, float* __restrict__ a1c){
  int bb = threadIdx.x & 15, jj = threadIdx.x >> 4;
  int j = blockIdx.x * 16 + jj;
  const float* x0 = embed + (long)words[bb * 256] * 512;
  const float* wr = w_ih1 + (long)j * 1024;
  float acc = 0.f;
  for(int k = 0; k < 512; k += 4){
    float4 a = *(const float4*)(x0 + k);
    float4 b = *(const float4*)(wr + k);
    acc += a.x*b.x + a.y*b.y + a.z*b.z + a.w*b.w;
  }
  a1c[bb * 2048 + j] = acc + b_ih1[j] + b_hh1[j];
}

// ---------- recurrent kernel: LDS weights + tagged fence-free exchange ----------
// 256 blocks. bl<128: layer-1, 4 units (fp32 W 32KB). bl>=128: layer-2, 4 units (fp16 W 32KB).
// h exchange: {tag,data} in one 8B relaxed agent atomic; consumers spin on tags while
// staging into swizzled LDS. No fences, no flags on the critical path. Ring depth 64.
// Backpressure: L1 checks L2 progress watermark every 16 steps (24-step margin).
__global__ void __launch_bounds__(256) k_recur(
    const float* __restrict__ w_hh1, const float* __restrict__ w_ih2, const float* __restrict__ w_hh2,
    const float* __restrict__ a1c, const float* __restrict__ b2c,
    ull* __restrict__ h1tag, ull* __restrict__ h2tag, unsigned short* __restrict__ h2bf,
    int* done){
  __shared__ float smem[16384];           // 64KB: [0..8192) = W, [8192..16384) = stage/partials
  float* stg = smem + 8192;
  int* prog2 = done + 2048;               // L2 progress watermark, flag i at [i*16]
  const int bl = blockIdx.x, tid = threadIdx.x;
  const int cg = tid & 3, kg = (tid >> 2) & 31, bh = tid >> 7;
  const int xr = (kg >> 1) & 7;
  const bool isL1 = (bl < 128);
  const int ubase = (isL1 ? bl : bl - 128) * 4;
  const int gb = tid >> 4, gu = tid & 3;
  const bool gate = ((tid & 12) == 0);

  // ---- stage weights into LDS (once; R11-proven layout+swizzle) ----
  if(isL1){
    #pragma unroll
    for(int q = 0; q < 8; ++q){
      int f = q * 256 + tid;
      int col = f >> 7, sk = f & 127;
      int row = (col >> 2) * 512 + ubase + (col & 3);
      float4 v = *(const float4*)(w_hh1 + (long)row * 512 + sk * 4);
      int key = (col + (col >> 2)) & 7;
      *(float4*)(smem + col * 512 + (sk ^ key) * 4) = v;
    }
  } else {
    unsigned short* W2 = (unsigned short*)smem;
    #pragma unroll
    for(int q = 0; q < 8; ++q){
      int f = q * 256 + tid;
      int col = f >> 7, sk = f & 127;
      int row = (col >> 2) * 512 + ubase + (col & 3);
      int k = sk * 8;
      const float* srcw = (k < 512) ? (w_ih2 + (long)row * 512 + k)
                                    : (w_hh2 + (long)row * 512 + (k - 512));
      float4 va = *(const float4*)(srcw);
      float4 vb = *(const float4*)(srcw + 4);
      ushort8 o;
      o[0] = __half_as_ushort(__float2half(va.x)); o[1] = __half_as_ushort(__float2half(va.y));
      o[2] = __half_as_ushort(__float2half(va.z)); o[3] = __half_as_ushort(__float2half(va.w));
      o[4] = __half_as_ushort(__float2half(vb.x)); o[5] = __half_as_ushort(__float2half(vb.y));
      o[6] = __half_as_ushort(__float2half(vb.z)); o[7] = __half_as_ushort(__float2half(vb.w));
      int key = (col + (col >> 2)) & 7;
      *(ushort8*)(W2 + col * 1024 + (sk ^ key) * 8) = o;
    }
  }
  float ag[4] = {0.f, 0.f, 0.f, 0.f};
  float cst = 0.f;
  if(gate){
    #pragma unroll
    for(int g = 0; g < 4; ++g)
      ag[g] = isL1 ? a1c[gb * 2048 + g * 512 + ubase + gu] : b2c[g * 512 + ubase + gu];
  }
  __syncthreads();

  for(int s = 1; s <= 255; ++s){
    // ---- ring backpressure (L1 only, rare, off critical path) ----
    if(isL1 && ((s & 15) == 1) && s > 48 && tid < 64){
      for(;;){
        int ok = (aldr(prog2 + tid * 16) >= s - 40) & (aldr(prog2 + (64 + tid) * 16) >= s - 40);
        if(__all(ok)) break;
        __builtin_amdgcn_s_sleep(1);
      }
    }

    float acc[8][4] = {};
    const int nph = isL1 ? 1 : 2;
    for(int p = 0; p < nph; ++p){
      // ---- spin-stage one 32KB h chunk from tagged ring into swizzled LDS ----
      const ull* src; unsigned want;
      if(isL1)      { src = h1tag + ((s - 1) & 63) * 8192; want = (unsigned)(s - 1); }
      else if(p==0) { src = h1tag + (s & 63) * 8192;       want = (unsigned)s; }
      else          { src = h2tag + ((s - 1) & 63) * 8192; want = (unsigned)(s - 1); }
      #pragma unroll
      for(int hf = 0; hf < 2; ++hf){
        ull v[16];
        #pragma unroll
        for(int j = 0; j < 16; ++j) v[j] = ald8(src + tid + 256 * (hf * 16 + j));
        for(;;){
          bool bad = false;
          #pragma unroll
          for(int j = 0; j < 16; ++j)
            if((unsigned)(v[j] >> 32) != want){ v[j] = ald8(src + tid + 256 * (hf * 16 + j)); bad = true; }
          if(!bad) break;
        }
        #pragma unroll
        for(int j = 0; j < 16; ++j){
          int u = tid + 256 * (hf * 16 + j);
          int slot = u >> 2;
          stg[4 * (slot ^ ((slot >> 3) & 7)) + (u & 3)] = __uint_as_float((unsigned)v[j]);
        }
      }
      __syncthreads();
      // ---- dot (R11-proven) ----
      if(isL1){
        #pragma unroll
        for(int jb = 0; jb < 4; ++jb){
          int sk = kg * 4 + jb;
          float4 wv[4];
          #pragma unroll
          for(int cc = 0; cc < 4; ++cc){
            int col = cg * 4 + cc;
            wv[cc] = *(const float4*)(smem + col * 512 + ((sk ^ ((col + (col >> 2)) & 7)) * 4));
          }
          #pragma unroll
          for(int b8 = 0; b8 < 8; ++b8){
            int slot = (bh * 8 + b8) * 128 + sk;
            float4 hv = *(const float4*)(stg + 4 * (slot ^ xr));
            #pragma unroll
            for(int cc = 0; cc < 4; ++cc)
              acc[b8][cc] += hv.x*wv[cc].x + hv.y*wv[cc].y + hv.z*wv[cc].z + hv.w*wv[cc].w;
          }
        }
      } else {
        const unsigned short* W2 = (const unsigned short*)smem;
        #pragma unroll
        for(int jbp = 0; jbp < 2; ++jbp){
          float wf[4][8];
          #pragma unroll
          for(int cc = 0; cc < 4; ++cc){
            int col = cg * 4 + cc;
            int sk = p * 64 + kg * 2 + jbp;
            ushort8 wv = *(const ushort8*)(W2 + col * 1024 + ((sk ^ ((col + (col >> 2)) & 7)) * 8));
            #pragma unroll
            for(int e = 0; e < 8; ++e) wf[cc][e] = __half2float(__ushort_as_half(wv[e]));
          }
          #pragma unroll
          for(int b8 = 0; b8 < 8; ++b8){
            int slot0 = (bh * 8 + b8) * 128 + kg * 4 + jbp * 2;
            float4 h0 = *(const float4*)(stg + 4 * (slot0 ^ xr));
            float4 h1v = *(const float4*)(stg + 4 * ((slot0 + 1) ^ xr));
            #pragma unroll
            for(int cc = 0; cc < 4; ++cc)
              acc[b8][cc] += h0.x*wf[cc][0] + h0.y*wf[cc][1] + h0.z*wf[cc][2] + h0.w*wf[cc][3]
                           + h1v.x*wf[cc][4] + h1v.y*wf[cc][5] + h1v.z*wf[cc][6] + h1v.w*wf[cc][7];
          }
        }
      }
      __syncthreads();
    }

    // ---- partials -> LDS -> reduce -> gates (R11-proven) ----
    #pragma unroll
    for(int b8 = 0; b8 < 8; ++b8){
      int b = bh * 8 + b8;
      *(float4*)(stg + ((b * 32 + kg) * 16 + cg * 4)) =
          make_float4(acc[b8][0], acc[b8][1], acc[b8][2], acc[b8][3]);
    }
    __syncthreads();
    float sum = 0.f;
    {
      int b = tid >> 4, col = tid & 15;
      #pragma unroll
      for(int k2 = 0; k2 < 32; ++k2) sum += stg[(b * 32 + k2) * 16 + col];
    }
    {
      int r = tid & 63;
      float gv[4];
      #pragma unroll
      for(int g = 0; g < 4; ++g) gv[g] = __shfl(sum, (r & 48) + g * 4 + (r & 3), 64);
      if(gate){
        float g0 = gv[0] + ag[0], g1 = gv[1] + ag[1], g2 = gv[2] + ag[2], g3 = gv[3] + ag[3];
        cst = sigm(g1) * cst + sigm(g0) * tanhf(g2);
        float h = sigm(g3) * tanhf(cst);
        if(isL1){
          ast8(h1tag + (s & 63) * 8192 + gb * 512 + ubase + gu, packh(h, (unsigned)s));
        } else {
          ast8(h2tag + (s & 63) * 8192 + gb * 512 + ubase + gu, packh(h, (unsigned)s));
          h2bf[((long)s * 16 + gb) * 512 + ubase + gu] = f2bf(h);   // read by k_proj only
        }
      }
    }
    __syncthreads();                      // stg reads done before next step overwrites
    if(!isL1 && tid == 0) asti(prog2 + (bl - 128) * 16, s);
  }
}

// ---------- projection GEMM (unchanged, passing) ----------
__global__ void __launch_bounds__(256, 2) k_proj(const unsigned short* __restrict__ A,
                                                 const unsigned short* __restrict__ Bm,
                                                 const float* __restrict__ fc_b,
                                                 float* __restrict__ out){
  __shared__ __align__(16) unsigned short As[4096];   // [128][32]
  __shared__ __align__(16) unsigned short Bs[4096];   // [128][32]
  const int tid = threadIdx.x;
  const int lane = tid & 63, w = tid >> 6;
  const int wr = w >> 1, wc = w & 1;
  const long mbase = (long)blockIdx.y * 128;
  const long nbase = (long)blockIdx.x * 128;
  f32x4 acc[4][4] = {};

  const int lrow = lane >> 2;
  const int lcol = (lane & 3) * 8;
  for(int kt = 0; kt < 16; ++kt){
    #pragma unroll
    for(int r = 0; r < 2; ++r){
      const unsigned short* ga = A  + (mbase + r*64 + w*16 + lrow) * 512 + kt*32 + lcol;
      __builtin_amdgcn_global_load_lds((const __attribute__((address_space(1))) void*)ga,
          (__attribute__((address_space(3))) void*)((char*)As + r*4096 + w*1024), 16, 0, 0);
      const unsigned short* gb = Bm + (nbase + r*64 + w*16 + lrow) * 512 + kt*32 + lcol;
      __builtin_amdgcn_global_load_lds((const __attribute__((address_space(1))) void*)gb,
          (__attribute__((address_space(3))) void*)((char*)Bs + r*4096 + w*1024), 16, 0, 0);
    }
    __syncthreads();
    short8 af[4], bf[4];
    const int kro = (lane >> 4) * 8;
    #pragma unroll
    for(int m = 0; m < 4; ++m){
      af[m] = *(const short8*)(As + (wr*64 + m*16 + (lane & 15)) * 32 + kro);
      bf[m] = *(const short8*)(Bs + (wc*64 + m*16 + (lane & 15)) * 32 + kro);
    }
    #pragma unroll
    for(int m = 0; m < 4; ++m){
      #pragma unroll
      for(int n = 0; n < 4; ++n){
        acc[m][n] = __builtin_amdgcn_mfma_f32_16x16x32_bf16(af[m], bf[n], acc[m][n], 0, 0, 0);
      }
    }
    __syncthreads();
  }
  const int crow0 = (lane >> 4) * 4;
  const int ccol = lane & 15;
  float fb[4];
  #pragma unroll
  for(int n = 0; n < 4; ++n) fb[n] = fc_b[nbase + wc*64 + n*16 + ccol];
  #pragma unroll
  for(int m = 0; m < 4; ++m){
    #pragma unroll
    for(int j = 0; j < 4; ++j){
      long rr = mbase + wr*64 + m*16 + crow0 + j;
      int t = (int)(rr >> 4), b = (int)(rr & 15);
      float* orow = out + ((long)b * 256 + t) * 32000;
      #pragma unroll
      for(int n = 0; n < 4; ++n){
        float v = (t == 0) ? 0.f : (acc[m][n][j] + fb[n]);
        orow[nbase + wc*64 + n*16 + ccol] = v;
      }
    }
  }
}

extern "C" void kernel_launch(void* const* d_in, const int* in_sizes, int n_in,
                              void* d_out, int out_size, void* d_ws, size_t ws_size,
                              hipStream_t stream){
  const int*   words = (const int*)  d_in[0];
  const float* embed = (const float*)d_in[1];
  const float* fc_b  = (const float*)d_in[2];
  const float* w_ih1 = (const float*)d_in[3];
  const float* w_hh1 = (const float*)d_in[4];
  const float* b_ih1 = (const float*)d_in[5];
  const float* b_hh1 = (const float*)d_in[6];
  const float* w_ih2 = (const float*)d_in[7];
  const float* w_hh2 = (const float*)d_in[8];
  const float* b_ih2 = (const float*)d_in[9];
  const float* b_hh2 = (const float*)d_in[10];
  float* out = (float*)d_out;
  char* ws = (char*)d_ws;

  unsigned short* embed_bf = (unsigned short*)(ws + 0);          // 32,768,000 B
  unsigned short* h2bf     = (unsigned short*)(ws + 32768000);   //  4,194,304 B (4096x512)
  ull* h1tag = (ull*)(ws + 36962304);                            //  4,194,304 B (64 x 8192 ull)
  ull* h2tag = (ull*)(ws + 41156608);                            //  4,194,304 B
  float* a1c = (float*)(ws + 45350912);                          //    131,072 B (16x2048)
  float* b2c = (float*)(ws + 45481984);                          //      8,192 B
  int*   done = (int*) (ws + 45490176);                          //     16,384 B (4096 ints)
  // total 45,506,560 B

  k_embed_cvt<<<16000, 256, 0, stream>>>(embed, embed_bf);
  k_prep_misc<<<32, 256, 0, stream>>>(b_ih2, b_hh2, b2c, h1tag, h2tag, h2bf, done);
  k_a1const<<<128, 256, 0, stream>>>(words, embed, w_ih1, b_ih1, b_hh1, a1c);

  // k_recur needs only de-facto co-residency (no grid.sync). Coop launch when the
  // runtime accepts it; otherwise plain launch (the R3..R9 silent-failure fix).
  void* args[9];
  args[0] = (void*)&w_hh1; args[1] = (void*)&w_ih2; args[2] = (void*)&w_hh2;
  args[3] = (void*)&a1c;   args[4] = (void*)&b2c;
  args[5] = (void*)&h1tag; args[6] = (void*)&h2tag; args[7] = (void*)&h2bf;
  args[8] = (void*)&done;
  hipError_t ce = hipLaunchCooperativeKernel((const void*)k_recur, dim3(256), dim3(256),
                                             args, 0, stream);
  if(ce != hipSuccess){
    k_recur<<<dim3(256), dim3(256), 0, stream>>>(w_hh1, w_ih2, w_hh2, a1c, b2c,
                                                 h1tag, h2tag, h2bf, done);
  }

  k_proj<<<dim3(250, 32), 256, 0, stream>>>(h2bf, embed_bf, fc_b, out);
}

// Round 13
// 2132.836 us; speedup vs baseline: 2.1859x; 1.0236x over previous
//
#include <hip/hip_runtime.h>
#include <hip/hip_fp16.h>

typedef __attribute__((ext_vector_type(8))) short short8;
typedef __attribute__((ext_vector_type(8))) unsigned short ushort8;
typedef __attribute__((ext_vector_type(4))) float f32x4;
typedef unsigned long long ull;

__device__ __forceinline__ unsigned short f2bf(float f){
  unsigned u = __float_as_uint(f);
  u += 0x7FFFu + ((u >> 16) & 1u);
  return (unsigned short)(u >> 16);
}
__device__ __forceinline__ float sigm(float x){ return 1.f / (1.f + expf(-x)); }
__device__ __forceinline__ int aldr(const int* p){
  return __hip_atomic_load(p, __ATOMIC_RELAXED, __HIP_MEMORY_SCOPE_AGENT);
}
__device__ __forceinline__ ull ald8(const ull* p){
  return __hip_atomic_load(p, __ATOMIC_RELAXED, __HIP_MEMORY_SCOPE_AGENT);
}
__device__ __forceinline__ void ast8(ull* p, ull v){
  __hip_atomic_store(p, v, __ATOMIC_RELAXED, __HIP_MEMORY_SCOPE_AGENT);
}
__device__ __forceinline__ void asti(int* p, int v){
  __hip_atomic_store(p, v, __ATOMIC_RELAXED, __HIP_MEMORY_SCOPE_AGENT);
}
__device__ __forceinline__ ull packh(float h, unsigned tag){
  return ((ull)tag << 32) | (ull)__float_as_uint(h);
}

// ---------- prep kernels ----------

__global__ void k_embed_cvt(const float* __restrict__ e, unsigned short* __restrict__ ebf){
  long i = ((long)blockIdx.x * 256 + threadIdx.x) * 4;
  float4 v = *(const float4*)(e + i);
  ushort4 o;
  o.x = f2bf(v.x); o.y = f2bf(v.y); o.z = f2bf(v.z); o.w = f2bf(v.w);
  *(ushort4*)(ebf + i) = o;
}

// re-zero slot 0 of both tagged rings (tag0 = step-0 zeros), h2bf t=0 rows, prog flags
__global__ void k_prep_misc(const float* __restrict__ b_ih2, const float* __restrict__ b_hh2,
                            float* __restrict__ b2c, ull* __restrict__ h1tag0,
                            ull* __restrict__ h2tag0, unsigned short* __restrict__ h2bf0,
                            int* __restrict__ done){
  int i = blockIdx.x * 256 + threadIdx.x;   // 8192 threads
  h1tag0[i] = 0ull;
  h2tag0[i] = 0ull;
  h2bf0[i] = 0;
  if(i < 2048){ b2c[i] = b_ih2[i] + b_hh2[i]; }
  if(i < 4096){ done[i] = 0; }
}

__global__ void k_a1const(const int* __restrict__ words, const float* __restrict__ embed,
                          const float* __restrict__ w_ih1, const float* __restrict__ b_ih1,
                          const float* __restrict__ b_hh1, float* __restrict__ a1c){
  int bb = threadIdx.x & 15, jj = threadIdx.x >> 4;
  int j = blockIdx.x * 16 + jj;
  const float* x0 = embed + (long)words[bb * 256] * 512;
  const float* wr = w_ih1 + (long)j * 1024;
  float acc = 0.f;
  for(int k = 0; k < 512; k += 4){
    float4 a = *(const float4*)(x0 + k);
    float4 b = *(const float4*)(wr + k);
    acc += a.x*b.x + a.y*b.y + a.z*b.z + a.w*b.w;
  }
  a1c[bb * 2048 + j] = acc + b_ih1[j] + b_hh1[j];
}

// ---------- recurrent kernel: LDS weights + tagged exchange, L2 double-issue ----------
// 256 blocks. bl<128: layer-1, 4 units (fp32 W 32KB). bl>=128: layer-2, 4 units (fp16 W 32KB).
// h exchange: {tag,data} in one 8B relaxed agent atomic. L2 issues BOTH chunks' loads before
// the first spin so the second chunk's latency hides under phase-0 staging + dot.
__global__ void __launch_bounds__(256) k_recur(
    const float* __restrict__ w_hh1, const float* __restrict__ w_ih2, const float* __restrict__ w_hh2,
    const float* __restrict__ a1c, const float* __restrict__ b2c,
    ull* __restrict__ h1tag, ull* __restrict__ h2tag, unsigned short* __restrict__ h2bf,
    int* done){
  __shared__ float smem[16384];           // 64KB: [0..8192) = W, [8192..16384) = stage/partials
  float* stg = smem + 8192;
  int* prog2 = done + 2048;               // L2 progress watermark, flag i at [i*16]
  const int bl = blockIdx.x, tid = threadIdx.x;
  const int cg = tid & 3, kg = (tid >> 2) & 31, bh = tid >> 7;
  const int xr = (kg >> 1) & 7;
  const bool isL1 = (bl < 128);
  const int ubase = (isL1 ? bl : bl - 128) * 4;
  const int gb = tid >> 4, gu = tid & 3;
  const bool gate = ((tid & 12) == 0);

  // ---- stage weights into LDS (once; R11/R12-proven layout+swizzle) ----
  if(isL1){
    #pragma unroll
    for(int q = 0; q < 8; ++q){
      int f = q * 256 + tid;
      int col = f >> 7, sk = f & 127;
      int row = (col >> 2) * 512 + ubase + (col & 3);
      float4 v = *(const float4*)(w_hh1 + (long)row * 512 + sk * 4);
      int key = (col + (col >> 2)) & 7;
      *(float4*)(smem + col * 512 + (sk ^ key) * 4) = v;
    }
  } else {
    unsigned short* W2 = (unsigned short*)smem;
    #pragma unroll
    for(int q = 0; q < 8; ++q){
      int f = q * 256 + tid;
      int col = f >> 7, sk = f & 127;
      int row = (col >> 2) * 512 + ubase + (col & 3);
      int k = sk * 8;
      const float* srcw = (k < 512) ? (w_ih2 + (long)row * 512 + k)
                                    : (w_hh2 + (long)row * 512 + (k - 512));
      float4 va = *(const float4*)(srcw);
      float4 vb = *(const float4*)(srcw + 4);
      ushort8 o;
      o[0] = __half_as_ushort(__float2half(va.x)); o[1] = __half_as_ushort(__float2half(va.y));
      o[2] = __half_as_ushort(__float2half(va.z)); o[3] = __half_as_ushort(__float2half(va.w));
      o[4] = __half_as_ushort(__float2half(vb.x)); o[5] = __half_as_ushort(__float2half(vb.y));
      o[6] = __half_as_ushort(__float2half(vb.z)); o[7] = __half_as_ushort(__float2half(vb.w));
      int key = (col + (col >> 2)) & 7;
      *(ushort8*)(W2 + col * 1024 + (sk ^ key) * 8) = o;
    }
  }
  float ag[4] = {0.f, 0.f, 0.f, 0.f};
  float cst = 0.f;
  if(gate){
    #pragma unroll
    for(int g = 0; g < 4; ++g)
      ag[g] = isL1 ? a1c[gb * 2048 + g * 512 + ubase + gu] : b2c[g * 512 + ubase + gu];
  }
  __syncthreads();

  if(isL1){
    // ================= layer 1 (R12-identical) =================
    for(int s = 1; s <= 255; ++s){
      if(((s & 15) == 1) && s > 48 && tid < 64){
        for(;;){
          int ok = (aldr(prog2 + tid * 16) >= s - 40) & (aldr(prog2 + (64 + tid) * 16) >= s - 40);
          if(__all(ok)) break;
          __builtin_amdgcn_s_sleep(1);
        }
      }
      float acc[8][4] = {};
      {
        const ull* src = h1tag + ((s - 1) & 63) * 8192;
        unsigned want = (unsigned)(s - 1);
        #pragma unroll
        for(int hf = 0; hf < 2; ++hf){
          ull v[16];
          #pragma unroll
          for(int j = 0; j < 16; ++j) v[j] = ald8(src + tid + 256 * (hf * 16 + j));
          for(;;){
            bool bad = false;
            #pragma unroll
            for(int j = 0; j < 16; ++j)
              if((unsigned)(v[j] >> 32) != want){ v[j] = ald8(src + tid + 256 * (hf * 16 + j)); bad = true; }
            if(!bad) break;
          }
          #pragma unroll
          for(int j = 0; j < 16; ++j){
            int u = tid + 256 * (hf * 16 + j);
            int slot = u >> 2;
            stg[4 * (slot ^ ((slot >> 3) & 7)) + (u & 3)] = __uint_as_float((unsigned)v[j]);
          }
        }
        __syncthreads();
        #pragma unroll
        for(int jb = 0; jb < 4; ++jb){
          int sk = kg * 4 + jb;
          float4 wv[4];
          #pragma unroll
          for(int cc = 0; cc < 4; ++cc){
            int col = cg * 4 + cc;
            wv[cc] = *(const float4*)(smem + col * 512 + ((sk ^ ((col + (col >> 2)) & 7)) * 4));
          }
          #pragma unroll
          for(int b8 = 0; b8 < 8; ++b8){
            int slot = (bh * 8 + b8) * 128 + sk;
            float4 hv = *(const float4*)(stg + 4 * (slot ^ xr));
            #pragma unroll
            for(int cc = 0; cc < 4; ++cc)
              acc[b8][cc] += hv.x*wv[cc].x + hv.y*wv[cc].y + hv.z*wv[cc].z + hv.w*wv[cc].w;
          }
        }
        __syncthreads();
      }
      #pragma unroll
      for(int b8 = 0; b8 < 8; ++b8){
        int b = bh * 8 + b8;
        *(float4*)(stg + ((b * 32 + kg) * 16 + cg * 4)) =
            make_float4(acc[b8][0], acc[b8][1], acc[b8][2], acc[b8][3]);
      }
      __syncthreads();
      float sum = 0.f;
      {
        int b = tid >> 4, col = tid & 15;
        #pragma unroll
        for(int k2 = 0; k2 < 32; ++k2) sum += stg[(b * 32 + k2) * 16 + col];
      }
      {
        int r = tid & 63;
        float gv[4];
        #pragma unroll
        for(int g = 0; g < 4; ++g) gv[g] = __shfl(sum, (r & 48) + g * 4 + (r & 3), 64);
        if(gate){
          float g0 = gv[0] + ag[0], g1 = gv[1] + ag[1], g2 = gv[2] + ag[2], g3 = gv[3] + ag[3];
          cst = sigm(g1) * cst + sigm(g0) * tanhf(g2);
          float h = sigm(g3) * tanhf(cst);
          ast8(h1tag + (s & 63) * 8192 + gb * 512 + ubase + gu, packh(h, (unsigned)s));
        }
      }
      __syncthreads();
    }
  } else {
    // ================= layer 2: double-issue both chunks =================
    for(int s = 1; s <= 255; ++s){
      float acc[8][4] = {};
      const ull* s1 = h1tag + (s & 63) * 8192;           // want tag s
      const ull* s2 = h2tag + ((s - 1) & 63) * 8192;     // want tag s-1
      const unsigned w1 = (unsigned)s, w2 = (unsigned)(s - 1);
      ull v1[32], v2[32];
      #pragma unroll
      for(int j = 0; j < 32; ++j) v1[j] = ald8(s1 + tid + 256 * j);
      #pragma unroll
      for(int j = 0; j < 32; ++j) v2[j] = ald8(s2 + tid + 256 * j);
      // spin-fix h1 chunk
      for(;;){
        bool bad = false;
        #pragma unroll
        for(int j = 0; j < 32; ++j)
          if((unsigned)(v1[j] >> 32) != w1){ v1[j] = ald8(s1 + tid + 256 * j); bad = true; }
        if(!bad) break;
      }
      #pragma unroll
      for(int j = 0; j < 32; ++j){
        int u = tid + 256 * j;
        int slot = u >> 2;
        stg[4 * (slot ^ ((slot >> 3) & 7)) + (u & 3)] = __uint_as_float((unsigned)v1[j]);
      }
      __syncthreads();
      // dot phase 0 (K = h1(s), W2 cols k-half p=0)
      {
        const unsigned short* W2 = (const unsigned short*)smem;
        #pragma unroll
        for(int jbp = 0; jbp < 2; ++jbp){
          float wf[4][8];
          #pragma unroll
          for(int cc = 0; cc < 4; ++cc){
            int col = cg * 4 + cc;
            int sk = kg * 2 + jbp;
            ushort8 wv = *(const ushort8*)(W2 + col * 1024 + ((sk ^ ((col + (col >> 2)) & 7)) * 8));
            #pragma unroll
            for(int e = 0; e < 8; ++e) wf[cc][e] = __half2float(__ushort_as_half(wv[e]));
          }
          #pragma unroll
          for(int b8 = 0; b8 < 8; ++b8){
            int slot0 = (bh * 8 + b8) * 128 + kg * 4 + jbp * 2;
            float4 h0 = *(const float4*)(stg + 4 * (slot0 ^ xr));
            float4 h1v = *(const float4*)(stg + 4 * ((slot0 + 1) ^ xr));
            #pragma unroll
            for(int cc = 0; cc < 4; ++cc)
              acc[b8][cc] += h0.x*wf[cc][0] + h0.y*wf[cc][1] + h0.z*wf[cc][2] + h0.w*wf[cc][3]
                           + h1v.x*wf[cc][4] + h1v.y*wf[cc][5] + h1v.z*wf[cc][6] + h1v.w*wf[cc][7];
          }
        }
      }
      // spin-fix h2 chunk BEFORE the barrier: overlaps peers' lag with other waves' dots
      for(;;){
        bool bad = false;
        #pragma unroll
        for(int j = 0; j < 32; ++j)
          if((unsigned)(v2[j] >> 32) != w2){ v2[j] = ald8(s2 + tid + 256 * j); bad = true; }
        if(!bad) break;
      }
      __syncthreads();                      // all phase-0 stg reads done
      #pragma unroll
      for(int j = 0; j < 32; ++j){
        int u = tid + 256 * j;
        int slot = u >> 2;
        stg[4 * (slot ^ ((slot >> 3) & 7)) + (u & 3)] = __uint_as_float((unsigned)v2[j]);
      }
      __syncthreads();
      // dot phase 1 (K = h2(s-1), W2 cols k-half p=1)
      {
        const unsigned short* W2 = (const unsigned short*)smem;
        #pragma unroll
        for(int jbp = 0; jbp < 2; ++jbp){
          float wf[4][8];
          #pragma unroll
          for(int cc = 0; cc < 4; ++cc){
            int col = cg * 4 + cc;
            int sk = 64 + kg * 2 + jbp;
            ushort8 wv = *(const ushort8*)(W2 + col * 1024 + ((sk ^ ((col + (col >> 2)) & 7)) * 8));
            #pragma unroll
            for(int e = 0; e < 8; ++e) wf[cc][e] = __half2float(__ushort_as_half(wv[e]));
          }
          #pragma unroll
          for(int b8 = 0; b8 < 8; ++b8){
            int slot0 = (bh * 8 + b8) * 128 + kg * 4 + jbp * 2;
            float4 h0 = *(const float4*)(stg + 4 * (slot0 ^ xr));
            float4 h1v = *(const float4*)(stg + 4 * ((slot0 + 1) ^ xr));
            #pragma unroll
            for(int cc = 0; cc < 4; ++cc)
              acc[b8][cc] += h0.x*wf[cc][0] + h0.y*wf[cc][1] + h0.z*wf[cc][2] + h0.w*wf[cc][3]
                           + h1v.x*wf[cc][4] + h1v.y*wf[cc][5] + h1v.z*wf[cc][6] + h1v.w*wf[cc][7];
          }
        }
      }
      __syncthreads();
      // ---- partials -> LDS -> reduce -> gates ----
      #pragma unroll
      for(int b8 = 0; b8 < 8; ++b8){
        int b = bh * 8 + b8;
        *(float4*)(stg + ((b * 32 + kg) * 16 + cg * 4)) =
            make_float4(acc[b8][0], acc[b8][1], acc[b8][2], acc[b8][3]);
      }
      __syncthreads();
      float sum = 0.f;
      {
        int b = tid >> 4, col = tid & 15;
        #pragma unroll
        for(int k2 = 0; k2 < 32; ++k2) sum += stg[(b * 32 + k2) * 16 + col];
      }
      {
        int r = tid & 63;
        float gv[4];
        #pragma unroll
        for(int g = 0; g < 4; ++g) gv[g] = __shfl(sum, (r & 48) + g * 4 + (r & 3), 64);
        if(gate){
          float g0 = gv[0] + ag[0], g1 = gv[1] + ag[1], g2 = gv[2] + ag[2], g3 = gv[3] + ag[3];
          cst = sigm(g1) * cst + sigm(g0) * tanhf(g2);
          float h = sigm(g3) * tanhf(cst);
          ast8(h2tag + (s & 63) * 8192 + gb * 512 + ubase + gu, packh(h, (unsigned)s));
          h2bf[((long)s * 16 + gb) * 512 + ubase + gu] = f2bf(h);
        }
      }
      __syncthreads();
      if(tid == 0) asti(prog2 + (bl - 128) * 16, s);
    }
  }
}

// ---------- projection GEMM (unchanged, passing) ----------
__global__ void __launch_bounds__(256, 2) k_proj(const unsigned short* __restrict__ A,
                                                 const unsigned short* __restrict__ Bm,
                                                 const float* __restrict__ fc_b,
                                                 float* __restrict__ out){
  __shared__ __align__(16) unsigned short As[4096];   // [128][32]
  __shared__ __align__(16) unsigned short Bs[4096];   // [128][32]
  const int tid = threadIdx.x;
  const int lane = tid & 63, w = tid >> 6;
  const int wr = w >> 1, wc = w & 1;
  const long mbase = (long)blockIdx.y * 128;
  const long nbase = (long)blockIdx.x * 128;
  f32x4 acc[4][4] = {};

  const int lrow = lane >> 2;
  const int lcol = (lane & 3) * 8;
  for(int kt = 0; kt < 16; ++kt){
    #pragma unroll
    for(int r = 0; r < 2; ++r){
      const unsigned short* ga = A  + (mbase + r*64 + w*16 + lrow) * 512 + kt*32 + lcol;
      __builtin_amdgcn_global_load_lds((const __attribute__((address_space(1))) void*)ga,
          (__attribute__((address_space(3))) void*)((char*)As + r*4096 + w*1024), 16, 0, 0);
      const unsigned short* gb = Bm + (nbase + r*64 + w*16 + lrow) * 512 + kt*32 + lcol;
      __builtin_amdgcn_global_load_lds((const __attribute__((address_space(1))) void*)gb,
          (__attribute__((address_space(3))) void*)((char*)Bs + r*4096 + w*1024), 16, 0, 0);
    }
    __syncthreads();
    short8 af[4], bf[4];
    const int kro = (lane >> 4) * 8;
    #pragma unroll
    for(int m = 0; m < 4; ++m){
      af[m] = *(const short8*)(As + (wr*64 + m*16 + (lane & 15)) * 32 + kro);
      bf[m] = *(const short8*)(Bs + (wc*64 + m*16 + (lane & 15)) * 32 + kro);
    }
    #pragma unroll
    for(int m = 0; m < 4; ++m){
      #pragma unroll
      for(int n = 0; n < 4; ++n){
        acc[m][n] = __builtin_amdgcn_mfma_f32_16x16x32_bf16(af[m], bf[n], acc[m][n], 0, 0, 0);
      }
    }
    __syncthreads();
  }
  const int crow0 = (lane >> 4) * 4;
  const int ccol = lane & 15;
  float fb[4];
  #pragma unroll
  for(int n = 0; n < 4; ++n) fb[n] = fc_b[nbase + wc*64 + n*16 + ccol];
  #pragma unroll
  for(int m = 0; m < 4; ++m){
    #pragma unroll
    for(int j = 0; j < 4; ++j){
      long rr = mbase + wr*64 + m*16 + crow0 + j;
      int t = (int)(rr >> 4), b = (int)(rr & 15);
      float* orow = out + ((long)b * 256 + t) * 32000;
      #pragma unroll
      for(int n = 0; n < 4; ++n){
        float v = (t == 0) ? 0.f : (acc[m][n][j] + fb[n]);
        orow[nbase + wc*64 + n*16 + ccol] = v;
      }
    }
  }
}

extern "C" void kernel_launch(void* const* d_in, const int* in_sizes, int n_in,
                              void* d_out, int out_size, void* d_ws, size_t ws_size,
                              hipStream_t stream){
  const int*   words = (const int*)  d_in[0];
  const float* embed = (const float*)d_in[1];
  const float* fc_b  = (const float*)d_in[2];
  const float* w_ih1 = (const float*)d_in[3];
  const float* w_hh1 = (const float*)d_in[4];
  const float* b_ih1 = (const float*)d_in[5];
  const float* b_hh1 = (const float*)d_in[6];
  const float* w_ih2 = (const float*)d_in[7];
  const float* w_hh2 = (const float*)d_in[8];
  const float* b_ih2 = (const float*)d_in[9];
  const float* b_hh2 = (const float*)d_in[10];
  float* out = (float*)d_out;
  char* ws = (char*)d_ws;

  unsigned short* embed_bf = (unsigned short*)(ws + 0);          // 32,768,000 B
  unsigned short* h2bf     = (unsigned short*)(ws + 32768000);   //  4,194,304 B (4096x512)
  ull* h1tag = (ull*)(ws + 36962304);                            //  4,194,304 B (64 x 8192 ull)
  ull* h2tag = (ull*)(ws + 41156608);                            //  4,194,304 B
  float* a1c = (float*)(ws + 45350912);                          //    131,072 B (16x2048)
  float* b2c = (float*)(ws + 45481984);                          //      8,192 B
  int*   done = (int*) (ws + 45490176);                          //     16,384 B (4096 ints)
  // total 45,506,560 B

  k_embed_cvt<<<16000, 256, 0, stream>>>(embed, embed_bf);
  k_prep_misc<<<32, 256, 0, stream>>>(b_ih2, b_hh2, b2c, h1tag, h2tag, h2bf, done);
  k_a1const<<<128, 256, 0, stream>>>(words, embed, w_ih1, b_ih1, b_hh1, a1c);

  // k_recur needs only de-facto co-residency (no grid.sync). Coop launch when the
  // runtime accepts it; otherwise plain launch (the R3..R9 silent-failure fix).
  void* args[9];
  args[0] = (void*)&w_hh1; args[1] = (void*)&w_ih2; args[2] = (void*)&w_hh2;
  args[3] = (void*)&a1c;   args[4] = (void*)&b2c;
  args[5] = (void*)&h1tag; args[6] = (void*)&h2tag; args[7] = (void*)&h2bf;
  args[8] = (void*)&done;
  hipError_t ce = hipLaunchCooperativeKernel((const void*)k_recur, dim3(256), dim3(256),
                                             args, 0, stream);
  if(ce != hipSuccess){
    k_recur<<<dim3(256), dim3(256), 0, stream>>>(w_hh1, w_ih2, w_hh2, a1c, b2c,
                                                 h1tag, h2tag, h2bf, done);
  }

  k_proj<<<dim3(250, 32), 256, 0, stream>>>(h2bf, embed_bf, fc_b, out);
}

// Round 14
// 1937.374 us; speedup vs baseline: 2.4064x; 1.1009x over previous
//
#include <hip/hip_runtime.h>
#include <hip/hip_fp16.h>

typedef __attribute__((ext_vector_type(8))) short short8;
typedef __attribute__((ext_vector_type(8))) unsigned short ushort8;
typedef __attribute__((ext_vector_type(4))) float f32x4;
typedef unsigned long long ull;

__device__ __forceinline__ unsigned short f2bf(float f){
  unsigned u = __float_as_uint(f);
  u += 0x7FFFu + ((u >> 16) & 1u);
  return (unsigned short)(u >> 16);
}
__device__ __forceinline__ float sigm(float x){ return 1.f / (1.f + expf(-x)); }
__device__ __forceinline__ int aldr(const int* p){
  return __hip_atomic_load(p, __ATOMIC_RELAXED, __HIP_MEMORY_SCOPE_AGENT);
}
__device__ __forceinline__ ull ald8(const ull* p){
  return __hip_atomic_load(p, __ATOMIC_RELAXED, __HIP_MEMORY_SCOPE_AGENT);
}
__device__ __forceinline__ void ast8(ull* p, ull v){
  __hip_atomic_store(p, v, __ATOMIC_RELAXED, __HIP_MEMORY_SCOPE_AGENT);
}
__device__ __forceinline__ void asti(int* p, int v){
  __hip_atomic_store(p, v, __ATOMIC_RELAXED, __HIP_MEMORY_SCOPE_AGENT);
}
// {tag, fp16 pair} in one 8B atom
__device__ __forceinline__ ull pack2(float he, float ho, unsigned tag){
  unsigned lo = (unsigned)__half_as_ushort(__float2half(he))
              | ((unsigned)__half_as_ushort(__float2half(ho)) << 16);
  return ((ull)tag << 32) | (ull)lo;
}

// ---------- prep kernels ----------

__global__ void k_embed_cvt(const float* __restrict__ e, unsigned short* __restrict__ ebf){
  long i = ((long)blockIdx.x * 256 + threadIdx.x) * 4;
  float4 v = *(const float4*)(e + i);
  ushort4 o;
  o.x = f2bf(v.x); o.y = f2bf(v.y); o.z = f2bf(v.z); o.w = f2bf(v.w);
  *(ushort4*)(ebf + i) = o;
}

// re-zero slot 0 of both tagged rings (tag0 = step-0 zeros), h2bf t=0 rows, prog flags
__global__ void k_prep_misc(const float* __restrict__ b_ih2, const float* __restrict__ b_hh2,
                            float* __restrict__ b2c, ull* __restrict__ h1tag0,
                            ull* __restrict__ h2tag0, unsigned short* __restrict__ h2bf0,
                            int* __restrict__ done){
  int i = blockIdx.x * 256 + threadIdx.x;   // 8192 threads
  if(i < 4096){ h1tag0[i] = 0ull; h2tag0[i] = 0ull; }
  h2bf0[i] = 0;
  if(i < 2048){ b2c[i] = b_ih2[i] + b_hh2[i]; }
  if(i < 4096){ done[i] = 0; }
}

__global__ void k_a1const(const int* __restrict__ words, const float* __restrict__ embed,
                          const float* __restrict__ w_ih1, const float* __restrict__ b_ih1,
                          const float* __restrict__ b_hh1, float* __restrict__ a1c){
  int bb = threadIdx.x & 15, jj = threadIdx.x >> 4;
  int j = blockIdx.x * 16 + jj;
  const float* x0 = embed + (long)words[bb * 256] * 512;
  const float* wr = w_ih1 + (long)j * 1024;
  float acc = 0.f;
  for(int k = 0; k < 512; k += 4){
    float4 a = *(const float4*)(x0 + k);
    float4 b = *(const float4*)(wr + k);
    acc += a.x*b.x + a.y*b.y + a.z*b.z + a.w*b.w;
  }
  a1c[bb * 2048 + j] = acc + b_ih1[j] + b_hh1[j];
}

// ---------- recurrent kernel: fp16 wire, fp16 LDS weights, slim L1 critical path ----------
// 256 blocks. bl<128: layer-1 (fp16 W1 16KB + f32 stage 32KB + 2KB partials, 2 barriers).
// bl>=128: layer-2 (fp16 W2 32KB + f32 stage 32KB, R13 structure). Exchange: {tag,2xfp16}
// 8B relaxed agent atomics (ring depth 64). Coop launch with plain fallback.
__global__ void __launch_bounds__(256) k_recur(
    const float* __restrict__ w_hh1, const float* __restrict__ w_ih2, const float* __restrict__ w_hh2,
    const float* __restrict__ a1c, const float* __restrict__ b2c,
    ull* __restrict__ h1tag, ull* __restrict__ h2tag, unsigned short* __restrict__ h2bf,
    int* done){
  __shared__ float smem[16384];           // 64KB
  int* prog2 = done + 2048;               // L2 progress watermark, flag i at [i*16]
  const int bl = blockIdx.x, tid = threadIdx.x;
  const int cg = tid & 3, kg = (tid >> 2) & 31, bh = tid >> 7;
  const int xr = (kg >> 1) & 7;
  const bool isL1 = (bl < 128);
  const int ubase = (isL1 ? bl : bl - 128) * 4;
  const int gb = tid >> 4, gu = tid & 3;
  const bool gate = ((tid & 12) == 0);

  // ---- stage weights into LDS (once) ----
  if(isL1){
    unsigned short* W1h = (unsigned short*)smem;        // 16 cols x 512 fp16 = 16KB
    #pragma unroll
    for(int q = 0; q < 4; ++q){
      int f = q * 256 + tid;                            // 0..1023 ushort8 slots
      int col = f >> 6, sk = f & 63;
      int row = (col >> 2) * 512 + ubase + (col & 3);
      const float* srcw = w_hh1 + (long)row * 512 + sk * 8;
      float4 va = *(const float4*)(srcw);
      float4 vb = *(const float4*)(srcw + 4);
      ushort8 o;
      o[0] = __half_as_ushort(__float2half(va.x)); o[1] = __half_as_ushort(__float2half(va.y));
      o[2] = __half_as_ushort(__float2half(va.z)); o[3] = __half_as_ushort(__float2half(va.w));
      o[4] = __half_as_ushort(__float2half(vb.x)); o[5] = __half_as_ushort(__float2half(vb.y));
      o[6] = __half_as_ushort(__float2half(vb.z)); o[7] = __half_as_ushort(__float2half(vb.w));
      int key = (col + (col >> 2)) & 7;
      *(ushort8*)(W1h + col * 512 + (sk ^ key) * 8) = o;
    }
  } else {
    unsigned short* W2 = (unsigned short*)smem;         // 16 cols x 1024 fp16 = 32KB
    #pragma unroll
    for(int q = 0; q < 8; ++q){
      int f = q * 256 + tid;
      int col = f >> 7, sk = f & 127;
      int row = (col >> 2) * 512 + ubase + (col & 3);
      int k = sk * 8;
      const float* srcw = (k < 512) ? (w_ih2 + (long)row * 512 + k)
                                    : (w_hh2 + (long)row * 512 + (k - 512));
      float4 va = *(const float4*)(srcw);
      float4 vb = *(const float4*)(srcw + 4);
      ushort8 o;
      o[0] = __half_as_ushort(__float2half(va.x)); o[1] = __half_as_ushort(__float2half(va.y));
      o[2] = __half_as_ushort(__float2half(va.z)); o[3] = __half_as_ushort(__float2half(va.w));
      o[4] = __half_as_ushort(__float2half(vb.x)); o[5] = __half_as_ushort(__float2half(vb.y));
      o[6] = __half_as_ushort(__float2half(vb.z)); o[7] = __half_as_ushort(__float2half(vb.w));
      int key = (col + (col >> 2)) & 7;
      *(ushort8*)(W2 + col * 1024 + (sk ^ key) * 8) = o;
    }
  }
  float ag[4] = {0.f, 0.f, 0.f, 0.f};
  float cst = 0.f;
  if(gate){
    #pragma unroll
    for(int g = 0; g < 4; ++g)
      ag[g] = isL1 ? a1c[gb * 2048 + g * 512 + ubase + gu] : b2c[g * 512 + ubase + gu];
  }
  __syncthreads();

  if(isL1){
    // ================= layer 1: 2-barrier step =================
    float* stg = smem + 4096;             // f32 stage 32KB at [16KB..48KB)
    float* prt = smem + 12288;            // partials 2KB at [48KB..50KB)
    for(int s = 1; s <= 255; ++s){
      if(((s & 15) == 1) && s > 48 && tid < 64){
        for(;;){
          int ok = (aldr(prog2 + tid * 16) >= s - 40) & (aldr(prog2 + (64 + tid) * 16) >= s - 40);
          if(__all(ok)) break;
          __builtin_amdgcn_s_sleep(1);
        }
      }
      // ---- spin-stage h1(s-1): 4096 packed words ----
      {
        const ull* src = h1tag + ((s - 1) & 63) * 4096;
        const unsigned want = (unsigned)(s - 1);
        ull v[16];
        #pragma unroll
        for(int j = 0; j < 16; ++j) v[j] = ald8(src + tid + 256 * j);
        for(;;){
          bool bad = false;
          #pragma unroll
          for(int j = 0; j < 16; ++j)
            if((unsigned)(v[j] >> 32) != want){ v[j] = ald8(src + tid + 256 * j); bad = true; }
          if(!bad) break;
        }
        #pragma unroll
        for(int j = 0; j < 16; ++j){
          unsigned lo = (unsigned)v[j];
          int slot = j * 128 + (tid >> 1);
          float* p = stg + 4 * (slot ^ ((slot >> 3) & 7)) + (tid & 1) * 2;
          p[0] = __half2float(__ushort_as_half((unsigned short)lo));
          p[1] = __half2float(__ushort_as_half((unsigned short)(lo >> 16)));
        }
      }
      __syncthreads();                    // barrier A: stage -> dot
      // ---- dot: fp16 W1, 512 MACs/thread ----
      float acc[8][4] = {};
      {
        const unsigned short* W1h = (const unsigned short*)smem;
        #pragma unroll
        for(int jbp = 0; jbp < 2; ++jbp){
          float wf[4][8];
          #pragma unroll
          for(int cc = 0; cc < 4; ++cc){
            int col = cg * 4 + cc;
            int sk = kg * 2 + jbp;
            ushort8 wv = *(const ushort8*)(W1h + col * 512 + ((sk ^ ((col + (col >> 2)) & 7)) * 8));
            #pragma unroll
            for(int e = 0; e < 8; ++e) wf[cc][e] = __half2float(__ushort_as_half(wv[e]));
          }
          #pragma unroll
          for(int b8 = 0; b8 < 8; ++b8){
            int slot0 = (bh * 8 + b8) * 128 + kg * 4 + jbp * 2;
            float4 h0 = *(const float4*)(stg + 4 * (slot0 ^ xr));
            float4 h1v = *(const float4*)(stg + 4 * ((slot0 + 1) ^ xr));
            #pragma unroll
            for(int cc = 0; cc < 4; ++cc)
              acc[b8][cc] += h0.x*wf[cc][0] + h0.y*wf[cc][1] + h0.z*wf[cc][2] + h0.w*wf[cc][3]
                           + h1v.x*wf[cc][4] + h1v.y*wf[cc][5] + h1v.z*wf[cc][6] + h1v.w*wf[cc][7];
          }
        }
      }
      // ---- in-wave butterfly over kg bits (lane bits 2..5) ----
      #pragma unroll
      for(int m = 4; m <= 32; m <<= 1){
        #pragma unroll
        for(int b8 = 0; b8 < 8; ++b8)
          #pragma unroll
          for(int cc = 0; cc < 4; ++cc)
            acc[b8][cc] += __shfl_xor(acc[b8][cc], m);
      }
      if((tid & 60) == 0){                // 4 lanes/wave (one per cg)
        int w = tid >> 6;
        #pragma unroll
        for(int cc = 0; cc < 4; ++cc)
          #pragma unroll
          for(int b8 = 0; b8 < 8; ++b8)
            prt[w * 128 + cg * 32 + cc * 8 + b8] = acc[b8][cc];
      }
      __syncthreads();                    // barrier B: partials -> gates
      // ---- gates (all lanes; cst valid on gate lanes) ----
      {
        int bhh = gb >> 3, b8g = gb & 7;
        float g0 = prt[(bhh*2)*128 + 0*32 + gu*8 + b8g] + prt[(bhh*2+1)*128 + 0*32 + gu*8 + b8g] + ag[0];
        float g1 = prt[(bhh*2)*128 + 1*32 + gu*8 + b8g] + prt[(bhh*2+1)*128 + 1*32 + gu*8 + b8g] + ag[1];
        float g2 = prt[(bhh*2)*128 + 2*32 + gu*8 + b8g] + prt[(bhh*2+1)*128 + 2*32 + gu*8 + b8g] + ag[2];
        float g3 = prt[(bhh*2)*128 + 3*32 + gu*8 + b8g] + prt[(bhh*2+1)*128 + 3*32 + gu*8 + b8g] + ag[3];
        cst = sigm(g1) * cst + sigm(g0) * tanhf(g2);
        float h = sigm(g3) * tanhf(cst);
        float hn = __shfl(h, ((tid & 63) + 1) & 63);
        if(gate && (gu & 1) == 0)
          ast8(h1tag + (s & 63) * 4096 + gb * 256 + bl * 2 + (gu >> 1), pack2(h, hn, (unsigned)s));
      }
      // no end barrier needed: stg/prt write-after-read protected by barriers A/B of next iter
    }
  } else {
    // ================= layer 2: R13 structure, fp16 wire =================
    float* stg = smem + 8192;             // f32 stage 32KB at [32KB..64KB)
    for(int s = 1; s <= 255; ++s){
      float acc[8][4] = {};
      const ull* s1 = h1tag + (s & 63) * 4096;           // want tag s
      const ull* s2 = h2tag + ((s - 1) & 63) * 4096;     // want tag s-1
      const unsigned w1 = (unsigned)s, w2 = (unsigned)(s - 1);
      ull v1[16], v2[16];
      #pragma unroll
      for(int j = 0; j < 16; ++j) v1[j] = ald8(s1 + tid + 256 * j);
      #pragma unroll
      for(int j = 0; j < 16; ++j) v2[j] = ald8(s2 + tid + 256 * j);
      for(;;){
        bool bad = false;
        #pragma unroll
        for(int j = 0; j < 16; ++j)
          if((unsigned)(v1[j] >> 32) != w1){ v1[j] = ald8(s1 + tid + 256 * j); bad = true; }
        if(!bad) break;
      }
      #pragma unroll
      for(int j = 0; j < 16; ++j){
        unsigned lo = (unsigned)v1[j];
        int slot = j * 128 + (tid >> 1);
        float* p = stg + 4 * (slot ^ ((slot >> 3) & 7)) + (tid & 1) * 2;
        p[0] = __half2float(__ushort_as_half((unsigned short)lo));
        p[1] = __half2float(__ushort_as_half((unsigned short)(lo >> 16)));
      }
      __syncthreads();
      // dot phase 0 (K = h1(s))
      {
        const unsigned short* W2 = (const unsigned short*)smem;
        #pragma unroll
        for(int jbp = 0; jbp < 2; ++jbp){
          float wf[4][8];
          #pragma unroll
          for(int cc = 0; cc < 4; ++cc){
            int col = cg * 4 + cc;
            int sk = kg * 2 + jbp;
            ushort8 wv = *(const ushort8*)(W2 + col * 1024 + ((sk ^ ((col + (col >> 2)) & 7)) * 8));
            #pragma unroll
            for(int e = 0; e < 8; ++e) wf[cc][e] = __half2float(__ushort_as_half(wv[e]));
          }
          #pragma unroll
          for(int b8 = 0; b8 < 8; ++b8){
            int slot0 = (bh * 8 + b8) * 128 + kg * 4 + jbp * 2;
            float4 h0 = *(const float4*)(stg + 4 * (slot0 ^ xr));
            float4 h1v = *(const float4*)(stg + 4 * ((slot0 + 1) ^ xr));
            #pragma unroll
            for(int cc = 0; cc < 4; ++cc)
              acc[b8][cc] += h0.x*wf[cc][0] + h0.y*wf[cc][1] + h0.z*wf[cc][2] + h0.w*wf[cc][3]
                           + h1v.x*wf[cc][4] + h1v.y*wf[cc][5] + h1v.z*wf[cc][6] + h1v.w*wf[cc][7];
          }
        }
      }
      // spin-fix h2 chunk before the barrier (overlaps peers' lag)
      for(;;){
        bool bad = false;
        #pragma unroll
        for(int j = 0; j < 16; ++j)
          if((unsigned)(v2[j] >> 32) != w2){ v2[j] = ald8(s2 + tid + 256 * j); bad = true; }
        if(!bad) break;
      }
      __syncthreads();                    // phase-0 stg reads done
      #pragma unroll
      for(int j = 0; j < 16; ++j){
        unsigned lo = (unsigned)v2[j];
        int slot = j * 128 + (tid >> 1);
        float* p = stg + 4 * (slot ^ ((slot >> 3) & 7)) + (tid & 1) * 2;
        p[0] = __half2float(__ushort_as_half((unsigned short)lo));
        p[1] = __half2float(__ushort_as_half((unsigned short)(lo >> 16)));
      }
      __syncthreads();
      // dot phase 1 (K = h2(s-1))
      {
        const unsigned short* W2 = (const unsigned short*)smem;
        #pragma unroll
        for(int jbp = 0; jbp < 2; ++jbp){
          float wf[4][8];
          #pragma unroll
          for(int cc = 0; cc < 4; ++cc){
            int col = cg * 4 + cc;
            int sk = 64 + kg * 2 + jbp;
            ushort8 wv = *(const ushort8*)(W2 + col * 1024 + ((sk ^ ((col + (col >> 2)) & 7)) * 8));
            #pragma unroll
            for(int e = 0; e < 8; ++e) wf[cc][e] = __half2float(__ushort_as_half(wv[e]));
          }
          #pragma unroll
          for(int b8 = 0; b8 < 8; ++b8){
            int slot0 = (bh * 8 + b8) * 128 + kg * 4 + jbp * 2;
            float4 h0 = *(const float4*)(stg + 4 * (slot0 ^ xr));
            float4 h1v = *(const float4*)(stg + 4 * ((slot0 + 1) ^ xr));
            #pragma unroll
            for(int cc = 0; cc < 4; ++cc)
              acc[b8][cc] += h0.x*wf[cc][0] + h0.y*wf[cc][1] + h0.z*wf[cc][2] + h0.w*wf[cc][3]
                           + h1v.x*wf[cc][4] + h1v.y*wf[cc][5] + h1v.z*wf[cc][6] + h1v.w*wf[cc][7];
          }
        }
      }
      __syncthreads();
      // partials -> LDS -> reduce -> gates (R12-proven)
      #pragma unroll
      for(int b8 = 0; b8 < 8; ++b8){
        int b = bh * 8 + b8;
        *(float4*)(stg + ((b * 32 + kg) * 16 + cg * 4)) =
            make_float4(acc[b8][0], acc[b8][1], acc[b8][2], acc[b8][3]);
      }
      __syncthreads();
      float sum = 0.f;
      {
        int b = tid >> 4, col = tid & 15;
        #pragma unroll
        for(int k2 = 0; k2 < 32; ++k2) sum += stg[(b * 32 + k2) * 16 + col];
      }
      {
        int r = tid & 63;
        float gv[4];
        #pragma unroll
        for(int g = 0; g < 4; ++g) gv[g] = __shfl(sum, (r & 48) + g * 4 + (r & 3), 64);
        float g0 = gv[0] + ag[0], g1 = gv[1] + ag[1], g2 = gv[2] + ag[2], g3 = gv[3] + ag[3];
        cst = sigm(g1) * cst + sigm(g0) * tanhf(g2);
        float h = sigm(g3) * tanhf(cst);
        float hn = __shfl(h, ((tid & 63) + 1) & 63);
        if(gate){
          if((gu & 1) == 0)
            ast8(h2tag + (s & 63) * 4096 + gb * 256 + (bl - 128) * 2 + (gu >> 1),
                 pack2(h, hn, (unsigned)s));
          h2bf[((long)s * 16 + gb) * 512 + ubase + gu] = f2bf(h);
        }
      }
      __syncthreads();
      if(tid == 0) asti(prog2 + (bl - 128) * 16, s);
    }
  }
}

// ---------- projection GEMM (unchanged, passing) ----------
__global__ void __launch_bounds__(256, 2) k_proj(const unsigned short* __restrict__ A,
                                                 const unsigned short* __restrict__ Bm,
                                                 const float* __restrict__ fc_b,
                                                 float* __restrict__ out){
  __shared__ __align__(16) unsigned short As[4096];   // [128][32]
  __shared__ __align__(16) unsigned short Bs[4096];   // [128][32]
  const int tid = threadIdx.x;
  const int lane = tid & 63, w = tid >> 6;
  const int wr = w >> 1, wc = w & 1;
  const long mbase = (long)blockIdx.y * 128;
  const long nbase = (long)blockIdx.x * 128;
  f32x4 acc[4][4] = {};

  const int lrow = lane >> 2;
  const int lcol = (lane & 3) * 8;
  for(int kt = 0; kt < 16; ++kt){
    #pragma unroll
    for(int r = 0; r < 2; ++r){
      const unsigned short* ga = A  + (mbase + r*64 + w*16 + lrow) * 512 + kt*32 + lcol;
      __builtin_amdgcn_global_load_lds((const __attribute__((address_space(1))) void*)ga,
          (__attribute__((address_space(3))) void*)((char*)As + r*4096 + w*1024), 16, 0, 0);
      const unsigned short* gb = Bm + (nbase + r*64 + w*16 + lrow) * 512 + kt*32 + lcol;
      __builtin_amdgcn_global_load_lds((const __attribute__((address_space(1))) void*)gb,
          (__attribute__((address_space(3))) void*)((char*)Bs + r*4096 + w*1024), 16, 0, 0);
    }
    __syncthreads();
    short8 af[4], bf[4];
    const int kro = (lane >> 4) * 8;
    #pragma unroll
    for(int m = 0; m < 4; ++m){
      af[m] = *(const short8*)(As + (wr*64 + m*16 + (lane & 15)) * 32 + kro);
      bf[m] = *(const short8*)(Bs + (wc*64 + m*16 + (lane & 15)) * 32 + kro);
    }
    #pragma unroll
    for(int m = 0; m < 4; ++m){
      #pragma unroll
      for(int n = 0; n < 4; ++n){
        acc[m][n] = __builtin_amdgcn_mfma_f32_16x16x32_bf16(af[m], bf[n], acc[m][n], 0, 0, 0);
      }
    }
    __syncthreads();
  }
  const int crow0 = (lane >> 4) * 4;
  const int ccol = lane & 15;
  float fb[4];
  #pragma unroll
  for(int n = 0; n < 4; ++n) fb[n] = fc_b[nbase + wc*64 + n*16 + ccol];
  #pragma unroll
  for(int m = 0; m < 4; ++m){
    #pragma unroll
    for(int j = 0; j < 4; ++j){
      long rr = mbase + wr*64 + m*16 + crow0 + j;
      int t = (int)(rr >> 4), b = (int)(rr & 15);
      float* orow = out + ((long)b * 256 + t) * 32000;
      #pragma unroll
      for(int n = 0; n < 4; ++n){
        float v = (t == 0) ? 0.f : (acc[m][n][j] + fb[n]);
        orow[nbase + wc*64 + n*16 + ccol] = v;
      }
    }
  }
}

extern "C" void kernel_launch(void* const* d_in, const int* in_sizes, int n_in,
                              void* d_out, int out_size, void* d_ws, size_t ws_size,
                              hipStream_t stream){
  const int*   words = (const int*)  d_in[0];
  const float* embed = (const float*)d_in[1];
  const float* fc_b  = (const float*)d_in[2];
  const float* w_ih1 = (const float*)d_in[3];
  const float* w_hh1 = (const float*)d_in[4];
  const float* b_ih1 = (const float*)d_in[5];
  const float* b_hh1 = (const float*)d_in[6];
  const float* w_ih2 = (const float*)d_in[7];
  const float* w_hh2 = (const float*)d_in[8];
  const float* b_ih2 = (const float*)d_in[9];
  const float* b_hh2 = (const float*)d_in[10];
  float* out = (float*)d_out;
  char* ws = (char*)d_ws;

  unsigned short* embed_bf = (unsigned short*)(ws + 0);          // 32,768,000 B
  unsigned short* h2bf     = (unsigned short*)(ws + 32768000);   //  4,194,304 B (4096x512)
  ull* h1tag = (ull*)(ws + 36962304);                            //  2,097,152 B (64 x 4096 ull)
  ull* h2tag = (ull*)(ws + 39059456);                            //  2,097,152 B
  float* a1c = (float*)(ws + 41156608);                          //    131,072 B (16x2048)
  float* b2c = (float*)(ws + 41287680);                          //      8,192 B
  int*   done = (int*) (ws + 41295872);                          //     16,384 B (4096 ints)
  // total 41,312,256 B

  k_embed_cvt<<<16000, 256, 0, stream>>>(embed, embed_bf);
  k_prep_misc<<<32, 256, 0, stream>>>(b_ih2, b_hh2, b2c, h1tag, h2tag, h2bf, done);
  k_a1const<<<128, 256, 0, stream>>>(words, embed, w_ih1, b_ih1, b_hh1, a1c);

  // k_recur needs only de-facto co-residency (no grid.sync). Coop launch when the
  // runtime accepts it; otherwise plain launch (the R3..R9 silent-failure fix).
  void* args[9];
  args[0] = (void*)&w_hh1; args[1] = (void*)&w_ih2; args[2] = (void*)&w_hh2;
  args[3] = (void*)&a1c;   args[4] = (void*)&b2c;
  args[5] = (void*)&h1tag; args[6] = (void*)&h2tag; args[7] = (void*)&h2bf;
  args[8] = (void*)&done;
  hipError_t ce = hipLaunchCooperativeKernel((const void*)k_recur, dim3(256), dim3(256),
                                             args, 0, stream);
  if(ce != hipSuccess){
    k_recur<<<dim3(256), dim3(256), 0, stream>>>(w_hh1, w_ih2, w_hh2, a1c, b2c,
                                                 h1tag, h2tag, h2bf, done);
  }

  k_proj<<<dim3(250, 32), 256, 0, stream>>>(h2bf, embed_bf, fc_b, out);
}